// Round 1
// baseline (530.166 us; speedup 1.0000x reference)
//
#include <hip/hip_runtime.h>
#include <stdint.h>

// Match numpy op-for-op rounding: no FMA contraction anywhere.
#pragma clang fp contract(off)

#define BATCH 8
#define HH 64
#define WW 64
#define KA 9
#define NBOX (HH * WW * KA)   // 36864 per batch
#define TOPN 2000
#define NPAD 2048
#define NW 32                 // 64-bit words covering 2048 bits
#define IOU_T 0.7f
#define MINSZ 0.01f
#define EPSF 1e-7f

__device__ __forceinline__ float clamp01(float x) { return fminf(fmaxf(x, 0.0f), 1.0f); }

// ---------------------------------------------------------------------------
// 1) Decode: per (b,h,w,k) box -> clipped box4 + validity-masked score key.
//    Layouts: scores (b,h,w,K) flat == gid; offsets (b,h,w,K,4) flat == gid*4.
// ---------------------------------------------------------------------------
__global__ __launch_bounds__(256) void decode_kernel(
    const float* __restrict__ scores, const float* __restrict__ offsets,
    const float* __restrict__ anchors, float4* __restrict__ boxes,
    unsigned* __restrict__ keys)
{
    int gid = blockIdx.x * 256 + threadIdx.x;
    if (gid >= BATCH * NBOX) return;
    int b = gid / NBOX;
    int t = gid - b * NBOX;
    int k = t % KA;
    int pos = t / KA;
    int wx = pos & (WW - 1);
    int hy = pos >> 6;

    float s = scores[gid];
    const float* off = offsets + (size_t)gid * 4;
    float ox = off[0], oy = off[1], ow = off[2], oh = off[3];
    float aw = anchors[2 * k], ah = anchors[2 * k + 1];
    float cx = ((float)wx + 0.5f) * 16.0f;
    float cy = ((float)hy + 0.5f) * 16.0f;

    float pw = (expf(ow) * aw) / 1024.0f;   // pred_wh = exp(off)*anc/img_wh
    float ph = (expf(oh) * ah) / 1024.0f;
    float xc = (aw * ox + cx) / 1024.0f;    // pred_xcyc = (anc*off + center)/img_wh
    float yc = (ah * oy + cy) / 1024.0f;

    float x1 = clamp01(xc - pw * 0.5f);
    float y1 = clamp01(yc - ph * 0.5f);
    float x2 = clamp01(xc + pw * 0.5f);
    float y2 = clamp01(yc + ph * 0.5f);
    float sc = clamp01(s);

    float m = ((x2 - x1) > MINSZ && (y2 - y1) > MINSZ) ? 1.0f : 0.0f;
    boxes[gid] = make_float4(x1 * m, y1 * m, x2 * m, y2 * m);
    // scores >= 0 so float bit pattern order == value order for unsigned compare
    keys[gid] = __float_as_uint(sc * m);
}

// ---------------------------------------------------------------------------
// 2) Exact top-2000 per batch: 4-round radix select on score bits (desc),
//    ties broken by ascending index (first R equals in index order).
//    Compacts selected items (arbitrary slot order; sort fixes order later).
// ---------------------------------------------------------------------------
__global__ __launch_bounds__(256) void select_kernel(
    const unsigned* __restrict__ keys, const float4* __restrict__ boxes,
    unsigned long long* __restrict__ selKeys, float4* __restrict__ selBoxes)
{
    int b = blockIdx.x;
    int tid = threadIdx.x;
    int lane = tid & 63;
    int wv = tid >> 6;

    __shared__ unsigned hist[256];
    __shared__ unsigned sh_prefix;
    __shared__ int sh_rank;
    __shared__ int wtot[4];
    __shared__ int runOff;
    __shared__ int slotCtr;

    if (tid == 0) { sh_prefix = 0u; sh_rank = TOPN; runOff = 0; slotCtr = 0; }
    // zero the 48 pad slots (sort to the tail; never written to output)
    if (tid < NPAD - TOPN) {
        selKeys[b * NPAD + TOPN + tid] = 0ull;
        selBoxes[b * NPAD + TOPN + tid] = make_float4(0, 0, 0, 0);
    }
    const unsigned* kb = keys + (size_t)b * NBOX;

    for (int round = 0; round < 4; ++round) {
        int shift = 24 - 8 * round;
        hist[tid] = 0;
        __syncthreads();
        unsigned pref = sh_prefix;
        for (int i = tid; i < NBOX; i += 256) {
            unsigned key = kb[i];
            // round 0: (u64)key >> 32 == 0 == pref, so all match
            if ((unsigned)(((unsigned long long)key) >> (shift + 8)) == pref)
                atomicAdd(&hist[(key >> shift) & 0xFFu], 1u);
        }
        __syncthreads();
        if (tid == 0) {
            int r = sh_rank;
            unsigned c = 0;
            int v = 255;
            for (; v >= 0; --v) {
                if (c + hist[v] >= (unsigned)r) break;
                c += hist[v];
            }
            sh_prefix = (sh_prefix << 8) | (unsigned)v;
            sh_rank = r - (int)c;
        }
        __syncthreads();
    }
    unsigned T = sh_prefix;   // exact score bits of the 2000th-largest
    int R = sh_rank;          // how many key==T to take (smallest indices)

    for (int base = 0; base < NBOX; base += 256) {
        int i = base + tid;   // NBOX % 256 == 0
        unsigned key = kb[i];
        bool eq = (key == T);
        bool gt = (key > T);
        unsigned long long bal = __ballot(eq);
        if (lane == 0) wtot[wv] = __popcll(bal);
        __syncthreads();
        int beforeW = 0;
        for (int q = 0; q < wv; ++q) beforeW += wtot[q];
        int myRank = runOff + beforeW + __popcll(bal & ((1ull << lane) - 1ull));
        bool take = gt || (eq && myRank < R);
        if (take) {
            int slot = atomicAdd(&slotCtr, 1);
            selKeys[b * NPAD + slot] =
                (((unsigned long long)key) << 32) |
                (unsigned long long)(0xFFFFFFFFu - (unsigned)i);
            selBoxes[b * NPAD + slot] = boxes[(size_t)b * NBOX + i];
        }
        __syncthreads();
        if (tid == 0) runOff += wtot[0] + wtot[1] + wtot[2] + wtot[3];
        __syncthreads();
    }
}

// ---------------------------------------------------------------------------
// 3) Bitonic sort 2048 keys (desc) in LDS; emit topBoxes in final order.
//    key = (score_bits<<32)|(~idx) -> desc key == score desc, index asc.
// ---------------------------------------------------------------------------
__global__ __launch_bounds__(1024) void sort_kernel(
    const unsigned long long* __restrict__ selKeys,
    const float4* __restrict__ selBoxes, float4* __restrict__ topBoxes)
{
    int b = blockIdx.x;
    int tid = threadIdx.x;
    __shared__ unsigned long long sk[NPAD];
    __shared__ unsigned short sp[NPAD];
    for (int i = tid; i < NPAD; i += 1024) { sk[i] = selKeys[b * NPAD + i]; sp[i] = (unsigned short)i; }
    __syncthreads();
    for (int k = 2; k <= NPAD; k <<= 1) {
        for (int j = k >> 1; j > 0; j >>= 1) {
#pragma unroll
            for (int n = 0; n < 2; ++n) {
                int i = tid + n * 1024;
                int ixj = i ^ j;
                if (ixj > i) {
                    bool desc = ((i & k) == 0);
                    unsigned long long a = sk[i], c = sk[ixj];
                    bool sw = desc ? (a < c) : (a > c);
                    if (sw) {
                        sk[i] = c; sk[ixj] = a;
                        unsigned short tp = sp[i]; sp[i] = sp[ixj]; sp[ixj] = tp;
                    }
                }
            }
            __syncthreads();
        }
    }
    for (int i = tid; i < NPAD; i += 1024) {
        float4 v = (i < TOPN) ? selBoxes[b * NPAD + sp[i]] : make_float4(0, 0, 0, 0);
        topBoxes[b * NPAD + i] = v;   // rows 2000..2047 zeroed for safe loads
    }
}

// ---------------------------------------------------------------------------
// 4) Suppression bitmask: one wave per row i; 32 ballots of 64 IOUs each.
//    sup[b][i][w] bit j64 = (iou(i, w*64+j64) > 0.7) && (j > i) && (j < 2000)
// ---------------------------------------------------------------------------
__global__ __launch_bounds__(256) void iou_kernel(
    const float4* __restrict__ topBoxes, unsigned long long* __restrict__ sup)
{
    int gid = blockIdx.x * 256 + threadIdx.x;
    int wid = gid >> 6;
    int lane = gid & 63;
    int b = wid / TOPN;
    int r = wid - b * TOPN;

    float4 A = topBoxes[(size_t)b * NPAD + r];
    float areaA = (A.z - A.x) * (A.w - A.y);
    size_t supBase = ((size_t)b * NPAD + r) * NW;

    for (int w = 0; w < NW; ++w) {
        int j = w * 64 + lane;
        float4 Bx = topBoxes[(size_t)b * NPAD + j];
        float ix1 = fmaxf(A.x, Bx.x);
        float iy1 = fmaxf(A.y, Bx.y);
        float ix2 = fminf(A.z, Bx.z);
        float iy2 = fminf(A.w, Bx.w);
        float iw = fmaxf(ix2 - ix1, 0.0f);
        float ih = fmaxf(iy2 - iy1, 0.0f);
        float inter = iw * ih;
        float areaB = (Bx.z - Bx.x) * (Bx.w - Bx.y);
        float iou = inter / (areaA + areaB - inter + EPSF);
        bool s = (iou > IOU_T) && (j > r) && (j < TOPN);
        unsigned long long m = __ballot(s);
        if (lane == 0) sup[supBase + w] = m;
    }
}

// ---------------------------------------------------------------------------
// 5) Sequential keep-mask resolution (exact fori_loop semantics) + scatter.
//    sup rows staged in 32KB LDS tiles; wave 0 resolves; then prefix-scatter.
// ---------------------------------------------------------------------------
__global__ __launch_bounds__(256) void resolve_kernel(
    const unsigned long long* __restrict__ sup,
    const float4* __restrict__ topBoxes, float4* __restrict__ out)
{
    int b = blockIdx.x;
    int tid = threadIdx.x;
    __shared__ unsigned long long tile[128 * NW];   // 32 KB
    __shared__ unsigned long long keep[NW];
    __shared__ int wbase[NW];

    if (tid < NW) keep[tid] = (tid < 31) ? ~0ull : 0xFFFFull;  // bits >=2000 off
    __syncthreads();

    for (int t0 = 0; t0 < TOPN; t0 += 128) {
        for (int off = tid; off < 128 * NW; off += 256)
            tile[off] = sup[((size_t)b * NPAD + t0) * NW + off];
        __syncthreads();
        if (tid < 64) {   // wave 0 only: wave-synchronous LDS updates
            int iend = (t0 + 128 < TOPN) ? (t0 + 128) : TOPN;
            for (int i = t0; i < iend; ++i) {
                unsigned long long kw = keep[i >> 6];
                if ((kw >> (i & 63)) & 1ull) {
                    if (tid < NW) keep[tid] &= ~tile[(i - t0) * NW + tid];
                }
            }
        }
        __syncthreads();
    }

    if (tid == 0) {
        int s = 0;
        for (int w2 = 0; w2 < NW; ++w2) { wbase[w2] = s; s += __popcll(keep[w2]); }
    }
    __syncthreads();
    for (int i = tid; i < TOPN; i += 256)
        out[(size_t)b * TOPN + i] = make_float4(0, 0, 0, 0);
    __syncthreads();
    for (int i = tid; i < TOPN; i += 256) {
        int wi = i >> 6, bz = i & 63;
        unsigned long long kw = keep[wi];
        if ((kw >> bz) & 1ull) {
            int pos = wbase[wi] + __popcll(kw & ((1ull << bz) - 1ull));
            out[(size_t)b * TOPN + pos] = topBoxes[(size_t)b * NPAD + i];
        }
    }
}

// ---------------------------------------------------------------------------
// Workspace layout (bytes):
//   boxes4   : 0                       size 8*36864*16 = 4,718,592
//   keys     : 4,718,592               size 8*36864*4  = 1,179,648
//   selKeys  : 5,898,240               size 8*2048*8   =   131,072
//   selBoxes : 6,029,312               size 8*2048*16  =   262,144
//   topBoxes : 6,291,456               size 8*2048*16  =   262,144
//   sup      : 6,553,600               size 8*2048*32*8= 4,194,304
//   total    : 10,747,904 (~10.3 MB)
// ---------------------------------------------------------------------------
extern "C" void kernel_launch(void* const* d_in, const int* in_sizes, int n_in,
                              void* d_out, int out_size, void* d_ws, size_t ws_size,
                              hipStream_t stream)
{
    const float* scores  = (const float*)d_in[0];
    const float* offsets = (const float*)d_in[1];
    const float* anchors = (const float*)d_in[2];
    float4* out = (float4*)d_out;

    char* ws = (char*)d_ws;
    float4*             boxes    = (float4*)(ws);
    unsigned*           keys     = (unsigned*)(ws + 4718592);
    unsigned long long* selKeys  = (unsigned long long*)(ws + 5898240);
    float4*             selBoxes = (float4*)(ws + 6029312);
    float4*             topBoxes = (float4*)(ws + 6291456);
    unsigned long long* sup      = (unsigned long long*)(ws + 6553600);

    decode_kernel<<<(BATCH * NBOX) / 256, 256, 0, stream>>>(scores, offsets, anchors, boxes, keys);
    select_kernel<<<BATCH, 256, 0, stream>>>(keys, boxes, selKeys, selBoxes);
    sort_kernel<<<BATCH, 1024, 0, stream>>>(selKeys, selBoxes, topBoxes);
    iou_kernel<<<(BATCH * TOPN * 64) / 256, 256, 0, stream>>>(topBoxes, sup);
    resolve_kernel<<<BATCH, 256, 0, stream>>>(sup, topBoxes, out);
}

// Round 2
// 476.577 us; speedup vs baseline: 1.1124x; 1.1124x over previous
//
#include <hip/hip_runtime.h>
#include <stdint.h>

// Match numpy op-for-op rounding: no FMA contraction anywhere.
#pragma clang fp contract(off)

#define BATCH 8
#define HH 64
#define WW 64
#define KA 9
#define NBOX (HH * WW * KA)   // 36864 per batch
#define TOPN 2000
#define NPAD 2048
#define NW 32                 // 64-bit words covering 2048 bits
#define NBINS 65536
#define IOU_T 0.7f
#define MINSZ 0.01f
#define EPSF 1e-7f

typedef unsigned int u32;
typedef unsigned long long u64;

__device__ __forceinline__ float clamp01(float x) { return fminf(fmaxf(x, 0.0f), 1.0f); }

// ---------------------------------------------------------------------------
// Shared box decode (bit-exact same arithmetic everywhere; contract off).
// ---------------------------------------------------------------------------
__device__ __forceinline__ void decode_one(
    const float* __restrict__ scores, const float4* __restrict__ offsets,
    const float* __restrict__ anchors, int gid, int t,
    float4* boxOut, u32* keyOut)
{
    int k = t % KA;
    int pos = t / KA;
    int wx = pos & (WW - 1);
    int hy = pos >> 6;
    float s = scores[gid];
    float4 off = offsets[gid];
    float aw = anchors[2 * k], ah = anchors[2 * k + 1];
    float cx = ((float)wx + 0.5f) * 16.0f;
    float cy = ((float)hy + 0.5f) * 16.0f;
    float pw = (expf(off.z) * aw) / 1024.0f;   // exp(off)*anc/img_wh
    float ph = (expf(off.w) * ah) / 1024.0f;
    float xc = (aw * off.x + cx) / 1024.0f;    // (anc*off + center)/img_wh
    float yc = (ah * off.y + cy) / 1024.0f;
    float x1 = clamp01(xc - pw * 0.5f);
    float y1 = clamp01(yc - ph * 0.5f);
    float x2 = clamp01(xc + pw * 0.5f);
    float y2 = clamp01(yc + ph * 0.5f);
    float sc = clamp01(s);
    float m = ((x2 - x1) > MINSZ && (y2 - y1) > MINSZ) ? 1.0f : 0.0f;
    *boxOut = make_float4(x1 * m, y1 * m, x2 * m, y2 * m);
    *keyOut = __float_as_uint(sc * m);   // score >= 0: bit order == value order
}

// ---------------------------------------------------------------------------
// 0) Zero the histogram/params region (graph-safe, no memset dependency).
// ---------------------------------------------------------------------------
__global__ __launch_bounds__(256) void zero_kernel(uint4* __restrict__ p, int n)
{
    int g = blockIdx.x * 256 + threadIdx.x;
    if (g < n) p[g] = make_uint4(0, 0, 0, 0);
}

// ---------------------------------------------------------------------------
// 1) Decode keys + round-1 histogram (top 16 bits of score key).
// ---------------------------------------------------------------------------
__global__ __launch_bounds__(256) void decode_kernel(
    const float* __restrict__ scores, const float4* __restrict__ offsets,
    const float* __restrict__ anchors, u32* __restrict__ keys,
    u32* __restrict__ hist1)
{
    int gid = blockIdx.x * 256 + threadIdx.x;   // grid exactly covers 8*NBOX
    int b = gid / NBOX;
    int t = gid - b * NBOX;
    float4 box; u32 key;
    decode_one(scores, offsets, anchors, gid, t, &box, &key);
    keys[gid] = key;
    atomicAdd(&hist1[(size_t)b * NBINS + (key >> 16)], 1u);
}

// ---------------------------------------------------------------------------
// 2/4/6) Suffix-scan a 65536-bin histogram from the top; find the bin where
// the descending cumulative count crosses rank r, and the residual rank.
// ---------------------------------------------------------------------------
__global__ __launch_bounds__(256) void scan_kernel(
    const u32* __restrict__ hist, const int* __restrict__ rankIn,
    u32* __restrict__ Pout, int* __restrict__ Rout)
{
    int b = blockIdx.x, tid = threadIdx.x;
    const u32* h = hist + (size_t)b * NBINS;
    const uint4* h4 = (const uint4*)(h + tid * 256);
    u32 s = 0;
    for (int j = 0; j < 64; ++j) { uint4 v = h4[j]; s += v.x + v.y + v.z + v.w; }
    __shared__ u32 suf[256];
    suf[tid] = s;
    __syncthreads();
    for (int d = 1; d < 256; d <<= 1) {
        u32 v = (tid + d < 256) ? suf[tid + d] : 0u;
        __syncthreads();
        suf[tid] += v;
        __syncthreads();
    }
    int r = rankIn ? rankIn[b] : TOPN;
    u32 mine = suf[tid];
    u32 nxt = (tid < 255) ? suf[tid + 1] : 0u;
    if (mine >= (u32)r && nxt < (u32)r) {          // exactly one thread
        u32 c = nxt;
        for (int v = tid * 256 + 255; v >= tid * 256; --v) {
            u32 hv = h[v];
            c += hv;
            if (c >= (u32)r) { Pout[b] = (u32)v; Rout[b] = r - (int)(c - hv); break; }
        }
    }
}

// ---------------------------------------------------------------------------
// 3) Round-2 histogram: low 16 score bits among keys whose top16 == P1.
// ---------------------------------------------------------------------------
__global__ __launch_bounds__(256) void hist2_kernel(
    const u32* __restrict__ keys, const u32* __restrict__ P, u32* __restrict__ hist2)
{
    int gid = blockIdx.x * 256 + threadIdx.x;
    int b = gid / NBOX;
    u32 key = keys[gid];
    if ((key >> 16) == P[b])
        atomicAdd(&hist2[(size_t)b * NBINS + (key & 0xFFFFu)], 1u);
}

// ---------------------------------------------------------------------------
// 5) Round-3 histogram: index key (0xFFFF - i) among keys == threshold score.
//    Bins have count 0/1 (indices unique) -> unique 48-bit threshold.
// ---------------------------------------------------------------------------
__global__ __launch_bounds__(256) void hist3_kernel(
    const u32* __restrict__ keys, const u32* __restrict__ P, u32* __restrict__ hist3)
{
    int gid = blockIdx.x * 256 + threadIdx.x;
    int b = gid / NBOX;
    int i = gid - b * NBOX;
    u32 key = keys[gid];
    u32 Sstar = (P[b] << 16) | P[8 + b];
    if (key == Sstar)
        atomicAdd(&hist3[(size_t)b * NBINS + (0xFFFFu - (u32)i)], 1u);
}

// ---------------------------------------------------------------------------
// 7) Compact: K48 = (score<<16)|(0xFFFF-i) >= T48 selects EXACTLY 2000 items
//    (all K48 distinct). Slot order arbitrary; sort fixes order. Boxes are
//    re-decoded only for the selected 2000 per batch.
// ---------------------------------------------------------------------------
__global__ __launch_bounds__(256) void compact_kernel(
    const u32* __restrict__ keys, const float* __restrict__ scores,
    const float4* __restrict__ offsets, const float* __restrict__ anchors,
    const u32* __restrict__ P, int* __restrict__ slotCtr,
    u64* __restrict__ selKeys, float4* __restrict__ selBoxes)
{
    // zero the 48 pad slots once (first 8 blocks)
    if (blockIdx.x < BATCH && threadIdx.x < (NPAD - TOPN)) {
        selKeys[(size_t)blockIdx.x * NPAD + TOPN + threadIdx.x] = 0ull;
        selBoxes[(size_t)blockIdx.x * NPAD + TOPN + threadIdx.x] = make_float4(0, 0, 0, 0);
    }
    int gid = blockIdx.x * 256 + threadIdx.x;
    int b = gid / NBOX;
    int i = gid - b * NBOX;
    u32 key = keys[gid];
    u64 T = ((u64)P[b] << 32) | ((u64)P[8 + b] << 16) | (u64)P[16 + b];
    u64 K = ((u64)key << 16) | (u64)(0xFFFFu - (u32)i);
    if (K >= T) {
        int slot = atomicAdd(&slotCtr[b], 1);
        float4 box; u32 k2;
        decode_one(scores, offsets, anchors, gid, i, &box, &k2);
        selKeys[(size_t)b * NPAD + slot] = K;
        selBoxes[(size_t)b * NPAD + slot] = box;
    }
}

// ---------------------------------------------------------------------------
// 8) Bitonic sort 2048 keys (desc) in LDS; emit topBoxes in final order.
//    Larger K48 == higher score, ties by smaller index. Pads (0) sort last.
// ---------------------------------------------------------------------------
__global__ __launch_bounds__(1024) void sort_kernel(
    const u64* __restrict__ selKeys, const float4* __restrict__ selBoxes,
    float4* __restrict__ topBoxes)
{
    int b = blockIdx.x;
    int tid = threadIdx.x;
    __shared__ u64 sk[NPAD];
    __shared__ unsigned short sp[NPAD];
    for (int i = tid; i < NPAD; i += 1024) { sk[i] = selKeys[b * NPAD + i]; sp[i] = (unsigned short)i; }
    __syncthreads();
    for (int k = 2; k <= NPAD; k <<= 1) {
        for (int j = k >> 1; j > 0; j >>= 1) {
#pragma unroll
            for (int n = 0; n < 2; ++n) {
                int i = tid + n * 1024;
                int ixj = i ^ j;
                if (ixj > i) {
                    bool desc = ((i & k) == 0);
                    u64 a = sk[i], c = sk[ixj];
                    bool sw = desc ? (a < c) : (a > c);
                    if (sw) {
                        sk[i] = c; sk[ixj] = a;
                        unsigned short tp = sp[i]; sp[i] = sp[ixj]; sp[ixj] = tp;
                    }
                }
            }
            __syncthreads();
        }
    }
    for (int i = tid; i < NPAD; i += 1024) {
        float4 v = (i < TOPN) ? selBoxes[b * NPAD + sp[i]] : make_float4(0, 0, 0, 0);
        topBoxes[b * NPAD + i] = v;   // rows 2000..2047 zeroed for safe loads
    }
}

// ---------------------------------------------------------------------------
// 9) Suppression bitmask, upper triangle only: row r writes words w >= r>>6.
// ---------------------------------------------------------------------------
__global__ __launch_bounds__(256) void iou_kernel(
    const float4* __restrict__ topBoxes, u64* __restrict__ sup)
{
    int gid = blockIdx.x * 256 + threadIdx.x;
    int wid = gid >> 6;
    int lane = gid & 63;
    int b = wid / TOPN;
    int r = wid - b * TOPN;

    float4 A = topBoxes[(size_t)b * NPAD + r];
    float areaA = (A.z - A.x) * (A.w - A.y);
    size_t supBase = ((size_t)b * NPAD + r) * NW;

    for (int w = r >> 6; w < NW; ++w) {
        int j = w * 64 + lane;
        float4 Bx = topBoxes[(size_t)b * NPAD + j];
        float ix1 = fmaxf(A.x, Bx.x);
        float iy1 = fmaxf(A.y, Bx.y);
        float ix2 = fminf(A.z, Bx.z);
        float iy2 = fminf(A.w, Bx.w);
        float iw = fmaxf(ix2 - ix1, 0.0f);
        float ih = fmaxf(iy2 - iy1, 0.0f);
        float inter = iw * ih;
        float areaB = (Bx.z - Bx.x) * (Bx.w - Bx.y);
        float iou = inter / (areaA + areaB - inter + EPSF);
        bool s = (iou > IOU_T) && (j > r) && (j < TOPN);
        u64 m = __ballot(s);
        if (lane == 0) sup[supBase + w] = m;
    }
}

// ---------------------------------------------------------------------------
// 10) Word-blocked NMS sweep (exact fori_loop semantics):
//     per 64-row word: register-serial diagonal resolve (readlane, no memory
//     in the dependent chain), then parallel scatter of kept rows' masks to
//     all later words. Then prefix-scatter kept boxes in index order.
// ---------------------------------------------------------------------------
__global__ __launch_bounds__(256) void resolve_kernel(
    const u64* __restrict__ sup, const float4* __restrict__ topBoxes,
    float4* __restrict__ out)
{
    int b = blockIdx.x;
    int tid = threadIdx.x;
    __shared__ u64 keep[NW];
    __shared__ int wbase[NW];
    if (tid < NW) keep[tid] = (tid < 31) ? ~0ull : 0xFFFFull;  // bits >=2000 off
    __syncthreads();
    const u64* supB = sup + (size_t)b * NPAD * NW;
    unsigned* keep32 = (unsigned*)keep;

    for (int w = 0; w < NW; ++w) {
        // phase 1: wave 0 resolves the 64x64 diagonal block serially in regs
        if (tid < 64) {
            u64 m = supB[(size_t)(w * 64 + tid) * NW + w];
            u32 mlo = (u32)m, mhi = (u32)(m >> 32);
            u64 kw = keep[w];
#pragma unroll
            for (int t2 = 0; t2 < 64; ++t2) {
                u32 alo = (u32)__builtin_amdgcn_readlane((int)mlo, t2);
                u32 ahi = (u32)__builtin_amdgcn_readlane((int)mhi, t2);
                u64 mt = ((u64)ahi << 32) | alo;
                u64 act = 0ull - ((kw >> t2) & 1ull);
                kw &= ~(mt & act);
            }
            if (tid == 0) keep[w] = kw;
        }
        __syncthreads();
        // phase 2: scatter kept rows' suppression to later words (parallel)
        u64 kwword = keep[w];
        int w2 = tid & 31;
        int grp = tid >> 5;              // 8 rows per thread, coalesced by w2
        if (w2 > w) {
            u64 acc = 0;
#pragma unroll
            for (int q = 0; q < 8; ++q) {
                int rl = grp * 8 + q;
                if ((kwword >> rl) & 1ull)
                    acc |= supB[(size_t)(w * 64 + rl) * NW + w2];
            }
            if (acc) {
                u32 lo = (u32)acc, hi = (u32)(acc >> 32);
                if (lo) atomicAnd(&keep32[2 * w2], ~lo);
                if (hi) atomicAnd(&keep32[2 * w2 + 1], ~hi);
            }
        }
        __syncthreads();
    }

    if (tid == 0) {
        int s = 0;
        for (int w2 = 0; w2 < NW; ++w2) { wbase[w2] = s; s += __popcll(keep[w2]); }
    }
    __syncthreads();
    for (int i = tid; i < TOPN; i += 256)
        out[(size_t)b * TOPN + i] = make_float4(0, 0, 0, 0);
    __syncthreads();
    for (int i = tid; i < TOPN; i += 256) {
        int wi = i >> 6, bz = i & 63;
        u64 kw = keep[wi];
        if ((kw >> bz) & 1ull) {
            int pos = wbase[wi] + __popcll(kw & ((1ull << bz) - 1ull));
            out[(size_t)b * TOPN + pos] = topBoxes[(size_t)b * NPAD + i];
        }
    }
}

// ---------------------------------------------------------------------------
// Workspace layout (bytes):
//   keys     : 0           size 8*36864*4   = 1,179,648
//   selKeys  : 1,179,648   size 8*2048*8    =   131,072
//   selBoxes : 1,310,720   size 8*2048*16   =   262,144
//   topBoxes : 1,572,864   size 8*2048*16   =   262,144
//   sup      : 1,835,008   size 8*2048*32*8 = 4,194,304
//   hist1    : 6,029,312   size 8*65536*4   = 2,097,152
//   hist2    : 8,126,464   size 8*65536*4   = 2,097,152
//   hist3    : 10,223,616  size 8*65536*4   = 2,097,152
//   params   : 12,320,768  size 512  (P[24] @0, R[24] @96, slotCtr[8] @192)
//   total    : 12,321,280 (~11.8 MB); zero region = hist1..params (6,291,968 B)
// ---------------------------------------------------------------------------
extern "C" void kernel_launch(void* const* d_in, const int* in_sizes, int n_in,
                              void* d_out, int out_size, void* d_ws, size_t ws_size,
                              hipStream_t stream)
{
    const float*  scores  = (const float*)d_in[0];
    const float4* offsets = (const float4*)d_in[1];
    const float*  anchors = (const float*)d_in[2];
    float4* out = (float4*)d_out;

    char* ws = (char*)d_ws;
    u32*    keys     = (u32*)(ws);
    u64*    selKeys  = (u64*)(ws + 1179648);
    float4* selBoxes = (float4*)(ws + 1310720);
    float4* topBoxes = (float4*)(ws + 1572864);
    u64*    sup      = (u64*)(ws + 1835008);
    u32*    hist1    = (u32*)(ws + 6029312);
    u32*    hist2    = (u32*)(ws + 8126464);
    u32*    hist3    = (u32*)(ws + 10223616);
    u32*    P        = (u32*)(ws + 12320768);
    int*    R        = (int*)(ws + 12320768 + 96);
    int*    slotCtr  = (int*)(ws + 12320768 + 192);

    const int ZERO_N = 6291968 / 16;   // hist1..params as uint4
    zero_kernel<<<(ZERO_N + 255) / 256, 256, 0, stream>>>((uint4*)(ws + 6029312), ZERO_N);
    decode_kernel<<<(BATCH * NBOX) / 256, 256, 0, stream>>>(scores, offsets, anchors, keys, hist1);
    scan_kernel<<<BATCH, 256, 0, stream>>>(hist1, nullptr, P + 0, R + 0);
    hist2_kernel<<<(BATCH * NBOX) / 256, 256, 0, stream>>>(keys, P, hist2);
    scan_kernel<<<BATCH, 256, 0, stream>>>(hist2, R + 0, P + 8, R + 8);
    hist3_kernel<<<(BATCH * NBOX) / 256, 256, 0, stream>>>(keys, P, hist3);
    scan_kernel<<<BATCH, 256, 0, stream>>>(hist3, R + 8, P + 16, R + 16);
    compact_kernel<<<(BATCH * NBOX) / 256, 256, 0, stream>>>(keys, scores, offsets, anchors,
                                                             P, slotCtr, selKeys, selBoxes);
    sort_kernel<<<BATCH, 1024, 0, stream>>>(selKeys, selBoxes, topBoxes);
    iou_kernel<<<(BATCH * TOPN * 64) / 256, 256, 0, stream>>>(topBoxes, sup);
    resolve_kernel<<<BATCH, 256, 0, stream>>>(sup, topBoxes, out);
}

// Round 3
// 238.136 us; speedup vs baseline: 2.2263x; 2.0013x over previous
//
#include <hip/hip_runtime.h>
#include <stdint.h>

// Match numpy op-for-op rounding: no FMA contraction anywhere.
#pragma clang fp contract(off)

#define BATCH 8
#define HH 64
#define WW 64
#define KA 9
#define NBOX (HH * WW * KA)   // 36864 per batch
#define TOPN 2000
#define NPAD 2048
#define NW 32                 // 64-bit words covering 2048 bits
#define NBINS 65536
#define IOU_T 0.7f
#define MINSZ 0.01f
#define EPSF 1e-7f

typedef unsigned int u32;
typedef unsigned long long u64;

__device__ __forceinline__ float clamp01(float x) { return fminf(fmaxf(x, 0.0f), 1.0f); }

// ---------------------------------------------------------------------------
// Shared box decode (bit-exact same arithmetic everywhere; contract off).
// ---------------------------------------------------------------------------
__device__ __forceinline__ void decode_one(
    const float* __restrict__ scores, const float4* __restrict__ offsets,
    const float* __restrict__ anchors, int gid, int t,
    float4* boxOut, u32* keyOut)
{
    int k = t % KA;
    int pos = t / KA;
    int wx = pos & (WW - 1);
    int hy = pos >> 6;
    float s = scores[gid];
    float4 off = offsets[gid];
    float aw = anchors[2 * k], ah = anchors[2 * k + 1];
    float cx = ((float)wx + 0.5f) * 16.0f;
    float cy = ((float)hy + 0.5f) * 16.0f;
    float pw = (expf(off.z) * aw) / 1024.0f;   // exp(off)*anc/img_wh
    float ph = (expf(off.w) * ah) / 1024.0f;
    float xc = (aw * off.x + cx) / 1024.0f;    // (anc*off + center)/img_wh
    float yc = (ah * off.y + cy) / 1024.0f;
    float x1 = clamp01(xc - pw * 0.5f);
    float y1 = clamp01(yc - ph * 0.5f);
    float x2 = clamp01(xc + pw * 0.5f);
    float y2 = clamp01(yc + ph * 0.5f);
    float sc = clamp01(s);
    float m = ((x2 - x1) > MINSZ && (y2 - y1) > MINSZ) ? 1.0f : 0.0f;
    *boxOut = make_float4(x1 * m, y1 * m, x2 * m, y2 * m);
    *keyOut = __float_as_uint(sc * m);   // score >= 0: bit order == value order
}

// ---------------------------------------------------------------------------
// 0) Zero hist1 + hist2 + selKeys + params (graph-safe re-init each call).
// ---------------------------------------------------------------------------
__global__ __launch_bounds__(256) void zero_kernel(uint4* __restrict__ p, int n)
{
    int g = blockIdx.x * 256 + threadIdx.x;
    if (g < n) p[g] = make_uint4(0, 0, 0, 0);
}

// ---------------------------------------------------------------------------
// 1) Decode keys + round-1 histogram (top 16 bits of score key).
// ---------------------------------------------------------------------------
__global__ __launch_bounds__(256) void decode_kernel(
    const float* __restrict__ scores, const float4* __restrict__ offsets,
    const float* __restrict__ anchors, u32* __restrict__ keys,
    u32* __restrict__ hist1)
{
    int gid = blockIdx.x * 256 + threadIdx.x;   // grid exactly covers 8*NBOX
    int b = gid / NBOX;
    int t = gid - b * NBOX;
    float4 box; u32 key;
    decode_one(scores, offsets, anchors, gid, t, &box, &key);
    keys[gid] = key;
    atomicAdd(&hist1[(size_t)b * NBINS + (key >> 16)], 1u);
}

// ---------------------------------------------------------------------------
// 2/4) Fully parallel rank-find in a 65536-bin histogram (descending):
//   level 1: 256 segment sums -> LDS suffix scan -> crossing segment
//   level 2: 256 bins of that segment -> LDS suffix scan -> crossing bin
// Outputs bin id P and residual rank R (count still needed inside bin P).
// ---------------------------------------------------------------------------
__global__ __launch_bounds__(256) void scan_kernel(
    const u32* __restrict__ hist, const int* __restrict__ rankIn,
    u32* __restrict__ Pout, int* __restrict__ Rout)
{
    int b = blockIdx.x, tid = threadIdx.x;
    const u32* h = hist + (size_t)b * NBINS;
    __shared__ u32 suf[256];
    __shared__ int sh_seg;
    // level 1: per-thread segment sum (256 bins, 64 x uint4)
    const uint4* h4 = (const uint4*)(h + tid * 256);
    u32 s = 0;
    for (int j = 0; j < 64; ++j) { uint4 v = h4[j]; s += v.x + v.y + v.z + v.w; }
    suf[tid] = s;
    __syncthreads();
    for (int d = 1; d < 256; d <<= 1) {
        u32 v = (tid + d < 256) ? suf[tid + d] : 0u;
        __syncthreads();
        suf[tid] += v;
        __syncthreads();
    }
    int r = rankIn ? rankIn[b] : TOPN;
    u32 mine = suf[tid];
    u32 nxt = (tid < 255) ? suf[tid + 1] : 0u;
    if (mine >= (u32)r && nxt < (u32)r) sh_seg = tid;   // exactly one thread
    __syncthreads();
    int seg = sh_seg;
    u32 base = (seg < 255) ? suf[seg + 1] : 0u;         // cum count above segment
    __syncthreads();
    // level 2: scan the 256 bins of the crossing segment
    suf[tid] = h[seg * 256 + tid];
    __syncthreads();
    for (int d = 1; d < 256; d <<= 1) {
        u32 v = (tid + d < 256) ? suf[tid + d] : 0u;
        __syncthreads();
        suf[tid] += v;
        __syncthreads();
    }
    u32 m2 = suf[tid] + base;
    u32 n2 = ((tid < 255) ? suf[tid + 1] : 0u) + base;
    if (m2 >= (u32)r && n2 < (u32)r) {
        Pout[b] = (u32)(seg * 256 + tid);
        Rout[b] = r - (int)n2;
    }
}

// ---------------------------------------------------------------------------
// 3) Round-2 histogram: low 16 score bits among keys whose top16 == P1.
// ---------------------------------------------------------------------------
__global__ __launch_bounds__(256) void hist2_kernel(
    const u32* __restrict__ keys, const u32* __restrict__ P, u32* __restrict__ hist2)
{
    int gid = blockIdx.x * 256 + threadIdx.x;
    int b = gid / NBOX;
    u32 key = keys[gid];
    if ((key >> 16) == P[b])
        atomicAdd(&hist2[(size_t)b * NBINS + (key & 0xFFFFu)], 1u);
}

// ---------------------------------------------------------------------------
// 5) Compact: take ALL keys >= Sstar (exactly 2000 + ties; ties sort past
//    slot 2000 and are zeroed). One atomic per block (no contention).
//    selKeys pre-zeroed by zero_kernel, so unwritten slots sort last.
// ---------------------------------------------------------------------------
__global__ __launch_bounds__(256) void compact_kernel(
    const u32* __restrict__ keys, const u32* __restrict__ P,
    int* __restrict__ slotCtr, u64* __restrict__ selKeys)
{
    int gid = blockIdx.x * 256 + threadIdx.x;
    int b = gid / NBOX;                 // uniform per block (NBOX % 256 == 0)
    int i = gid - b * NBOX;
    u32 key = keys[gid];
    u32 Sstar = (P[b] << 16) | P[8 + b];
    bool take = (key >= Sstar);
    int lane = threadIdx.x & 63, wv = threadIdx.x >> 6;
    u64 bal = __ballot(take);
    __shared__ int woff[4];
    if (lane == 0) woff[wv] = __popcll(bal);
    __syncthreads();
    if (threadIdx.x == 0) {
        int tot = woff[0] + woff[1] + woff[2] + woff[3];
        int base = tot ? atomicAdd(&slotCtr[b], tot) : 0;
        int acc = base;
        for (int q = 0; q < 4; ++q) { int c = woff[q]; woff[q] = acc; acc += c; }
    }
    __syncthreads();
    if (take) {
        int slot = woff[wv] + __popcll(bal & ((1ull << lane) - 1ull));
        if (slot < NPAD)   // safety vs pathological tie counts
            selKeys[(size_t)b * NPAD + slot] =
                ((u64)key << 16) | (u64)(0xFFFFu - (u32)i);
    }
}

// ---------------------------------------------------------------------------
// 6) Bitonic sort 2048 keys (desc, keys only, 16KB LDS); epilogue re-decodes
//    the top-2000 boxes straight from inputs (index = 0xFFFF - low16).
// ---------------------------------------------------------------------------
__global__ __launch_bounds__(1024) void sort_kernel(
    const u64* __restrict__ selKeys, const float* __restrict__ scores,
    const float4* __restrict__ offsets, const float* __restrict__ anchors,
    float4* __restrict__ topBoxes)
{
    int b = blockIdx.x;
    int tid = threadIdx.x;
    __shared__ u64 sk[NPAD];
    sk[tid] = selKeys[b * NPAD + tid];
    sk[tid + 1024] = selKeys[b * NPAD + tid + 1024];
    __syncthreads();
    for (int k = 2; k <= NPAD; k <<= 1) {
        for (int j = k >> 1; j > 0; j >>= 1) {
#pragma unroll
            for (int n = 0; n < 2; ++n) {
                int i = tid + n * 1024;
                int ixj = i ^ j;
                if (ixj > i) {
                    bool desc = ((i & k) == 0);
                    u64 a = sk[i], c = sk[ixj];
                    if (desc ? (a < c) : (a > c)) { sk[i] = c; sk[ixj] = a; }
                }
            }
            __syncthreads();
        }
    }
    for (int i = tid; i < NPAD; i += 1024) {
        float4 v = make_float4(0, 0, 0, 0);
        if (i < TOPN) {
            u64 K = sk[i];
            int idx = 0xFFFF - (int)(K & 0xFFFFull);
            u32 kdummy;
            decode_one(scores, offsets, anchors, b * NBOX + idx, idx, &v, &kdummy);
        }
        topBoxes[b * NPAD + i] = v;   // rows 2000..2047 zeroed for safe loads
    }
}

// ---------------------------------------------------------------------------
// 7) Suppression bitmask, upper triangle only: row r writes words w >= r>>6.
// ---------------------------------------------------------------------------
__global__ __launch_bounds__(256) void iou_kernel(
    const float4* __restrict__ topBoxes, u64* __restrict__ sup)
{
    int gid = blockIdx.x * 256 + threadIdx.x;
    int wid = gid >> 6;
    int lane = gid & 63;
    int b = wid / TOPN;
    int r = wid - b * TOPN;

    float4 A = topBoxes[(size_t)b * NPAD + r];
    float areaA = (A.z - A.x) * (A.w - A.y);
    size_t supBase = ((size_t)b * NPAD + r) * NW;

    for (int w = r >> 6; w < NW; ++w) {
        int j = w * 64 + lane;
        float4 Bx = topBoxes[(size_t)b * NPAD + j];
        float ix1 = fmaxf(A.x, Bx.x);
        float iy1 = fmaxf(A.y, Bx.y);
        float ix2 = fminf(A.z, Bx.z);
        float iy2 = fminf(A.w, Bx.w);
        float iw = fmaxf(ix2 - ix1, 0.0f);
        float ih = fmaxf(iy2 - iy1, 0.0f);
        float inter = iw * ih;
        float areaB = (Bx.z - Bx.x) * (Bx.w - Bx.y);
        float iou = inter / (areaA + areaB - inter + EPSF);
        bool s = (iou > IOU_T) && (j > r) && (j < TOPN);
        u64 m = __ballot(s);
        if (lane == 0) sup[supBase + w] = m;
    }
}

// ---------------------------------------------------------------------------
// 8) Word-blocked NMS sweep (exact fori_loop semantics):
//    per 64-row word: register-serial diagonal resolve (readlane chain),
//    then parallel apply of kept rows' masks to later words; prefix-scatter.
// ---------------------------------------------------------------------------
__global__ __launch_bounds__(256) void resolve_kernel(
    const u64* __restrict__ sup, const float4* __restrict__ topBoxes,
    float4* __restrict__ out)
{
    int b = blockIdx.x;
    int tid = threadIdx.x;
    __shared__ u64 keep[NW];
    __shared__ int wbase[NW];
    if (tid < NW) keep[tid] = (tid < 31) ? ~0ull : 0xFFFFull;  // bits >=2000 off
    __syncthreads();
    const u64* supB = sup + (size_t)b * NPAD * NW;
    unsigned* keep32 = (unsigned*)keep;

    for (int w = 0; w < NW; ++w) {
        // phase 1: wave 0 resolves the 64x64 diagonal block serially in regs
        if (tid < 64) {
            u64 m = supB[(size_t)(w * 64 + tid) * NW + w];
            u32 mlo = (u32)m, mhi = (u32)(m >> 32);
            u64 kw = keep[w];
#pragma unroll
            for (int t2 = 0; t2 < 64; ++t2) {
                u32 alo = (u32)__builtin_amdgcn_readlane((int)mlo, t2);
                u32 ahi = (u32)__builtin_amdgcn_readlane((int)mhi, t2);
                u64 mt = ((u64)ahi << 32) | alo;
                u64 act = 0ull - ((kw >> t2) & 1ull);
                kw &= ~(mt & act);
            }
            if (tid == 0) keep[w] = kw;
        }
        __syncthreads();
        // phase 2: scatter kept rows' suppression to later words (parallel)
        u64 kwword = keep[w];
        int w2 = tid & 31;
        int grp = tid >> 5;              // 8 rows per thread, coalesced by w2
        if (w2 > w) {
            u64 acc = 0;
#pragma unroll
            for (int q = 0; q < 8; ++q) {
                int rl = grp * 8 + q;
                if ((kwword >> rl) & 1ull)
                    acc |= supB[(size_t)(w * 64 + rl) * NW + w2];
            }
            if (acc) {
                u32 lo = (u32)acc, hi = (u32)(acc >> 32);
                if (lo) atomicAnd(&keep32[2 * w2], ~lo);
                if (hi) atomicAnd(&keep32[2 * w2 + 1], ~hi);
            }
        }
        __syncthreads();
    }

    if (tid == 0) {
        int s = 0;
        for (int w2 = 0; w2 < NW; ++w2) { wbase[w2] = s; s += __popcll(keep[w2]); }
    }
    __syncthreads();
    for (int i = tid; i < TOPN; i += 256)
        out[(size_t)b * TOPN + i] = make_float4(0, 0, 0, 0);
    __syncthreads();
    for (int i = tid; i < TOPN; i += 256) {
        int wi = i >> 6, bz = i & 63;
        u64 kw = keep[wi];
        if ((kw >> bz) & 1ull) {
            int pos = wbase[wi] + __popcll(kw & ((1ull << bz) - 1ull));
            out[(size_t)b * TOPN + pos] = topBoxes[(size_t)b * NPAD + i];
        }
    }
}

// ---------------------------------------------------------------------------
// Workspace layout (bytes):
//   sup      : 0           size 8*2048*32*8 = 4,194,304
//   keys     : 4,194,304   size 8*36864*4   = 1,179,648
//   topBoxes : 5,373,952   size 8*2048*16   =   262,144
//   --- zero region start ---
//   hist1    : 5,636,096   size 8*65536*4   = 2,097,152
//   hist2    : 7,733,248   size 8*65536*4   = 2,097,152
//   selKeys  : 9,830,400   size 8*2048*8    =   131,072
//   params   : 9,961,472   size 512   (P[16] @0, R[16] @64, slotCtr[8] @128)
//   total    : 9,961,984 (~9.5 MB); zero region = 4,325,888 B
// ---------------------------------------------------------------------------
extern "C" void kernel_launch(void* const* d_in, const int* in_sizes, int n_in,
                              void* d_out, int out_size, void* d_ws, size_t ws_size,
                              hipStream_t stream)
{
    const float*  scores  = (const float*)d_in[0];
    const float4* offsets = (const float4*)d_in[1];
    const float*  anchors = (const float*)d_in[2];
    float4* out = (float4*)d_out;

    char* ws = (char*)d_ws;
    u64*    sup      = (u64*)(ws);
    u32*    keys     = (u32*)(ws + 4194304);
    float4* topBoxes = (float4*)(ws + 5373952);
    u32*    hist1    = (u32*)(ws + 5636096);
    u32*    hist2    = (u32*)(ws + 7733248);
    u64*    selKeys  = (u64*)(ws + 9830400);
    u32*    P        = (u32*)(ws + 9961472);
    int*    R        = (int*)(ws + 9961472 + 64);
    int*    slotCtr  = (int*)(ws + 9961472 + 128);

    const int ZERO_N = 4325888 / 16;   // hist1..params as uint4
    zero_kernel<<<(ZERO_N + 255) / 256, 256, 0, stream>>>((uint4*)(ws + 5636096), ZERO_N);
    decode_kernel<<<(BATCH * NBOX) / 256, 256, 0, stream>>>(scores, offsets, anchors, keys, hist1);
    scan_kernel<<<BATCH, 256, 0, stream>>>(hist1, nullptr, P + 0, R + 0);
    hist2_kernel<<<(BATCH * NBOX) / 256, 256, 0, stream>>>(keys, P, hist2);
    scan_kernel<<<BATCH, 256, 0, stream>>>(hist2, R + 0, P + 8, R + 8);
    compact_kernel<<<(BATCH * NBOX) / 256, 256, 0, stream>>>(keys, P, slotCtr, selKeys);
    sort_kernel<<<BATCH, 1024, 0, stream>>>(selKeys, scores, offsets, anchors, topBoxes);
    iou_kernel<<<(BATCH * TOPN * 64) / 256, 256, 0, stream>>>(topBoxes, sup);
    resolve_kernel<<<BATCH, 256, 0, stream>>>(sup, topBoxes, out);
}

// Round 4
// 198.056 us; speedup vs baseline: 2.6768x; 1.2024x over previous
//
#include <hip/hip_runtime.h>
#include <stdint.h>

// Match numpy op-for-op rounding: no FMA contraction anywhere.
#pragma clang fp contract(off)

#define BATCH 8
#define HH 64
#define WW 64
#define KA 9
#define NBOX (HH * WW * KA)   // 36864 per batch
#define TOPN 2000
#define NPAD 2048
#define NW 32                 // 64-bit words covering 2048 bits
#define NBINS 65536
#define IOU_T 0.7f
#define MINSZ 0.01f
#define EPSF 1e-7f
#define TSTRIDE 33            // LDS tile row stride in u64 (bank-conflict-free)

typedef unsigned int u32;
typedef unsigned long long u64;

__device__ __forceinline__ float clamp01(float x) { return fminf(fmaxf(x, 0.0f), 1.0f); }

// ---------------------------------------------------------------------------
// Shared box decode (bit-exact same arithmetic everywhere; contract off).
// ---------------------------------------------------------------------------
__device__ __forceinline__ void decode_one(
    const float* __restrict__ scores, const float4* __restrict__ offsets,
    const float* __restrict__ anchors, int gid, int t,
    float4* boxOut, u32* keyOut)
{
    int k = t % KA;
    int pos = t / KA;
    int wx = pos & (WW - 1);
    int hy = pos >> 6;
    float s = scores[gid];
    float4 off = offsets[gid];
    float aw = anchors[2 * k], ah = anchors[2 * k + 1];
    float cx = ((float)wx + 0.5f) * 16.0f;
    float cy = ((float)hy + 0.5f) * 16.0f;
    float pw = (expf(off.z) * aw) / 1024.0f;   // exp(off)*anc/img_wh
    float ph = (expf(off.w) * ah) / 1024.0f;
    float xc = (aw * off.x + cx) / 1024.0f;    // (anc*off + center)/img_wh
    float yc = (ah * off.y + cy) / 1024.0f;
    float x1 = clamp01(xc - pw * 0.5f);
    float y1 = clamp01(yc - ph * 0.5f);
    float x2 = clamp01(xc + pw * 0.5f);
    float y2 = clamp01(yc + ph * 0.5f);
    float sc = clamp01(s);
    float m = ((x2 - x1) > MINSZ && (y2 - y1) > MINSZ) ? 1.0f : 0.0f;
    *boxOut = make_float4(x1 * m, y1 * m, x2 * m, y2 * m);
    *keyOut = __float_as_uint(sc * m);   // score >= 0: bit order == value order
}

// ---------------------------------------------------------------------------
// 0) Zero hist1 + hist2 + selKeys + params (graph-safe re-init each call).
// ---------------------------------------------------------------------------
__global__ __launch_bounds__(256) void zero_kernel(uint4* __restrict__ p, int n)
{
    int g = blockIdx.x * 256 + threadIdx.x;
    if (g < n) p[g] = make_uint4(0, 0, 0, 0);
}

// ---------------------------------------------------------------------------
// 1) Decode keys + round-1 histogram (top 16 bits of score key).
// ---------------------------------------------------------------------------
__global__ __launch_bounds__(256) void decode_kernel(
    const float* __restrict__ scores, const float4* __restrict__ offsets,
    const float* __restrict__ anchors, u32* __restrict__ keys,
    u32* __restrict__ hist1)
{
    int gid = blockIdx.x * 256 + threadIdx.x;   // grid exactly covers 8*NBOX
    int b = gid / NBOX;
    int t = gid - b * NBOX;
    float4 box; u32 key;
    decode_one(scores, offsets, anchors, gid, t, &box, &key);
    keys[gid] = key;
    atomicAdd(&hist1[(size_t)b * NBINS + (key >> 16)], 1u);
}

// ---------------------------------------------------------------------------
// 2/4) Fully parallel rank-find in a 65536-bin histogram (descending).
// ---------------------------------------------------------------------------
__global__ __launch_bounds__(256) void scan_kernel(
    const u32* __restrict__ hist, const int* __restrict__ rankIn,
    u32* __restrict__ Pout, int* __restrict__ Rout)
{
    int b = blockIdx.x, tid = threadIdx.x;
    const u32* h = hist + (size_t)b * NBINS;
    __shared__ u32 suf[256];
    __shared__ int sh_seg;
    const uint4* h4 = (const uint4*)(h + tid * 256);
    u32 s = 0;
    for (int j = 0; j < 64; ++j) { uint4 v = h4[j]; s += v.x + v.y + v.z + v.w; }
    suf[tid] = s;
    __syncthreads();
    for (int d = 1; d < 256; d <<= 1) {
        u32 v = (tid + d < 256) ? suf[tid + d] : 0u;
        __syncthreads();
        suf[tid] += v;
        __syncthreads();
    }
    int r = rankIn ? rankIn[b] : TOPN;
    u32 mine = suf[tid];
    u32 nxt = (tid < 255) ? suf[tid + 1] : 0u;
    if (mine >= (u32)r && nxt < (u32)r) sh_seg = tid;   // exactly one thread
    __syncthreads();
    int seg = sh_seg;
    u32 base = (seg < 255) ? suf[seg + 1] : 0u;         // cum count above segment
    __syncthreads();
    suf[tid] = h[seg * 256 + tid];
    __syncthreads();
    for (int d = 1; d < 256; d <<= 1) {
        u32 v = (tid + d < 256) ? suf[tid + d] : 0u;
        __syncthreads();
        suf[tid] += v;
        __syncthreads();
    }
    u32 m2 = suf[tid] + base;
    u32 n2 = ((tid < 255) ? suf[tid + 1] : 0u) + base;
    if (m2 >= (u32)r && n2 < (u32)r) {
        Pout[b] = (u32)(seg * 256 + tid);
        Rout[b] = r - (int)n2;
    }
}

// ---------------------------------------------------------------------------
// 3) Round-2 histogram: low 16 score bits among keys whose top16 == P1.
// ---------------------------------------------------------------------------
__global__ __launch_bounds__(256) void hist2_kernel(
    const u32* __restrict__ keys, const u32* __restrict__ P, u32* __restrict__ hist2)
{
    int gid = blockIdx.x * 256 + threadIdx.x;
    int b = gid / NBOX;
    u32 key = keys[gid];
    if ((key >> 16) == P[b])
        atomicAdd(&hist2[(size_t)b * NBINS + (key & 0xFFFFu)], 1u);
}

// ---------------------------------------------------------------------------
// 5) Compact: take ALL keys >= Sstar (ties sort past slot 2000 -> zeroed).
// ---------------------------------------------------------------------------
__global__ __launch_bounds__(256) void compact_kernel(
    const u32* __restrict__ keys, const u32* __restrict__ P,
    int* __restrict__ slotCtr, u64* __restrict__ selKeys)
{
    int gid = blockIdx.x * 256 + threadIdx.x;
    int b = gid / NBOX;                 // uniform per block (NBOX % 256 == 0)
    int i = gid - b * NBOX;
    u32 key = keys[gid];
    u32 Sstar = (P[b] << 16) | P[8 + b];
    bool take = (key >= Sstar);
    int lane = threadIdx.x & 63, wv = threadIdx.x >> 6;
    u64 bal = __ballot(take);
    __shared__ int woff[4];
    if (lane == 0) woff[wv] = __popcll(bal);
    __syncthreads();
    if (threadIdx.x == 0) {
        int tot = woff[0] + woff[1] + woff[2] + woff[3];
        int base = tot ? atomicAdd(&slotCtr[b], tot) : 0;
        int acc = base;
        for (int q = 0; q < 4; ++q) { int c = woff[q]; woff[q] = acc; acc += c; }
    }
    __syncthreads();
    if (take) {
        int slot = woff[wv] + __popcll(bal & ((1ull << lane) - 1ull));
        if (slot < NPAD)   // safety vs pathological tie counts
            selKeys[(size_t)b * NPAD + slot] =
                ((u64)key << 16) | (u64)(0xFFFFu - (u32)i);
    }
}

// ---------------------------------------------------------------------------
// 6) Bitonic sort 2048 keys (desc, keys only); epilogue re-decodes top-2000.
// ---------------------------------------------------------------------------
__global__ __launch_bounds__(1024) void sort_kernel(
    const u64* __restrict__ selKeys, const float* __restrict__ scores,
    const float4* __restrict__ offsets, const float* __restrict__ anchors,
    float4* __restrict__ topBoxes)
{
    int b = blockIdx.x;
    int tid = threadIdx.x;
    __shared__ u64 sk[NPAD];
    sk[tid] = selKeys[b * NPAD + tid];
    sk[tid + 1024] = selKeys[b * NPAD + tid + 1024];
    __syncthreads();
    for (int k = 2; k <= NPAD; k <<= 1) {
        for (int j = k >> 1; j > 0; j >>= 1) {
#pragma unroll
            for (int n = 0; n < 2; ++n) {
                int i = tid + n * 1024;
                int ixj = i ^ j;
                if (ixj > i) {
                    bool desc = ((i & k) == 0);
                    u64 a = sk[i], c = sk[ixj];
                    if (desc ? (a < c) : (a > c)) { sk[i] = c; sk[ixj] = a; }
                }
            }
            __syncthreads();
        }
    }
    for (int i = tid; i < NPAD; i += 1024) {
        float4 v = make_float4(0, 0, 0, 0);
        if (i < TOPN) {
            u64 K = sk[i];
            int idx = 0xFFFF - (int)(K & 0xFFFFull);
            u32 kdummy;
            decode_one(scores, offsets, anchors, b * NBOX + idx, idx, &v, &kdummy);
        }
        topBoxes[b * NPAD + i] = v;   // rows 2000..2047 zeroed for safe loads
    }
}

// ---------------------------------------------------------------------------
// 7) Suppression bitmask, upper triangle only: row r writes words w >= r>>6.
// ---------------------------------------------------------------------------
__global__ __launch_bounds__(256) void iou_kernel(
    const float4* __restrict__ topBoxes, u64* __restrict__ sup)
{
    int gid = blockIdx.x * 256 + threadIdx.x;
    int wid = gid >> 6;
    int lane = gid & 63;
    int b = wid / TOPN;
    int r = wid - b * TOPN;

    float4 A = topBoxes[(size_t)b * NPAD + r];
    float areaA = (A.z - A.x) * (A.w - A.y);
    size_t supBase = ((size_t)b * NPAD + r) * NW;

    for (int w = r >> 6; w < NW; ++w) {
        int j = w * 64 + lane;
        float4 Bx = topBoxes[(size_t)b * NPAD + j];
        float ix1 = fmaxf(A.x, Bx.x);
        float iy1 = fmaxf(A.y, Bx.y);
        float ix2 = fminf(A.z, Bx.z);
        float iy2 = fminf(A.w, Bx.w);
        float iw = fmaxf(ix2 - ix1, 0.0f);
        float ih = fmaxf(iy2 - iy1, 0.0f);
        float inter = iw * ih;
        float areaB = (Bx.z - Bx.x) * (Bx.w - Bx.y);
        float iou = inter / (areaA + areaB - inter + EPSF);
        bool s = (iou > IOU_T) && (j > r) && (j < TOPN);
        u64 m = __ballot(s);
        if (lane == 0) sup[supBase + w] = m;
    }
}

// ---------------------------------------------------------------------------
// 8) Word-blocked NMS sweep, double-buffered LDS tiles + 1-ahead register
//    prefetch. All sup data is static -> loads never wait on keep state:
//    iteration w issues coalesced loads for tile w+1 (64B/thread), resolves
//    tile w entirely from LDS, then writes regs->LDS alternate buffer.
// ---------------------------------------------------------------------------
__global__ __launch_bounds__(256) void resolve_kernel(
    const u64* __restrict__ sup, const float4* __restrict__ topBoxes,
    float4* __restrict__ out)
{
    int b = blockIdx.x;
    int tid = threadIdx.x;
    __shared__ u64 tile[2][64 * TSTRIDE];   // 2 x 16.9 KB
    __shared__ u64 keep[NW];
    __shared__ int wbase[NW];
    if (tid < NW) keep[tid] = (tid < 31) ? ~0ull : 0xFFFFull;  // bits >=2000 off
    const u64* supB = sup + (size_t)b * NPAD * NW;
    unsigned* keep32 = (unsigned*)keep;

    int row = tid >> 2;               // 0..63
    int wcol = (tid & 3) * 8;         // base word within row (8 consecutive)

    // prologue: load + stage tile 0 (rows 0..63, all 32 words; 16 KB)
    {
        const uint4* src = (const uint4*)(supB + tid * 8);
        uint4 p0 = src[0], p1 = src[1], p2 = src[2], p3 = src[3];
        u64* d = &tile[0][row * TSTRIDE + wcol];
        d[0] = ((u64)p0.y << 32) | p0.x;  d[1] = ((u64)p0.w << 32) | p0.z;
        d[2] = ((u64)p1.y << 32) | p1.x;  d[3] = ((u64)p1.w << 32) | p1.z;
        d[4] = ((u64)p2.y << 32) | p2.x;  d[5] = ((u64)p2.w << 32) | p2.z;
        d[6] = ((u64)p3.y << 32) | p3.x;  d[7] = ((u64)p3.w << 32) | p3.z;
    }
    __syncthreads();

    for (int w = 0; w < NW; ++w) {
        int buf = w & 1;
        // issue next tile's loads early (latency hides under this iteration)
        uint4 n0, n1, n2, n3;
        if (w + 1 < NW) {
            const uint4* src = (const uint4*)(supB + (size_t)(w + 1) * 2048 + tid * 8);
            n0 = src[0]; n1 = src[1]; n2 = src[2]; n3 = src[3];
        }

        // phase 1: wave 0 resolves the 64x64 diagonal block serially in regs
        if (tid < 64) {
            u64 m = tile[buf][tid * TSTRIDE + w];
            u32 mlo = (u32)m, mhi = (u32)(m >> 32);
            u64 kw = keep[w];
#pragma unroll
            for (int t2 = 0; t2 < 64; ++t2) {
                u32 alo = (u32)__builtin_amdgcn_readlane((int)mlo, t2);
                u32 ahi = (u32)__builtin_amdgcn_readlane((int)mhi, t2);
                u64 mt = ((u64)ahi << 32) | alo;
                u64 act = 0ull - ((kw >> t2) & 1ull);
                kw &= ~(mt & act);
            }
            if (tid == 0) keep[w] = kw;
        }
        __syncthreads();

        // phase 2: apply kept rows' suppression to later words (from LDS)
        u64 kwword = keep[w];
        int w2 = tid & 31;
        int grp = tid >> 5;              // 8 rows per thread
        if (w2 > w) {
            u64 acc = 0;
#pragma unroll
            for (int q = 0; q < 8; ++q) {
                int rl = grp * 8 + q;
                if ((kwword >> rl) & 1ull)
                    acc |= tile[buf][rl * TSTRIDE + w2];
            }
            if (acc) {
                u32 lo = (u32)acc, hi = (u32)(acc >> 32);
                if (lo) atomicAnd(&keep32[2 * w2], ~lo);
                if (hi) atomicAnd(&keep32[2 * w2 + 1], ~hi);
            }
        }

        // stage next tile into the alternate buffer (prev contents consumed)
        if (w + 1 < NW) {
            u64* d = &tile[buf ^ 1][row * TSTRIDE + wcol];
            d[0] = ((u64)n0.y << 32) | n0.x;  d[1] = ((u64)n0.w << 32) | n0.z;
            d[2] = ((u64)n1.y << 32) | n1.x;  d[3] = ((u64)n1.w << 32) | n1.z;
            d[4] = ((u64)n2.y << 32) | n2.x;  d[5] = ((u64)n2.w << 32) | n2.z;
            d[6] = ((u64)n3.y << 32) | n3.x;  d[7] = ((u64)n3.w << 32) | n3.z;
        }
        __syncthreads();
    }

    if (tid == 0) {
        int s = 0;
        for (int w2 = 0; w2 < NW; ++w2) { wbase[w2] = s; s += __popcll(keep[w2]); }
    }
    __syncthreads();
    for (int i = tid; i < TOPN; i += 256)
        out[(size_t)b * TOPN + i] = make_float4(0, 0, 0, 0);
    __syncthreads();
    for (int i = tid; i < TOPN; i += 256) {
        int wi = i >> 6, bz = i & 63;
        u64 kw = keep[wi];
        if ((kw >> bz) & 1ull) {
            int pos = wbase[wi] + __popcll(kw & ((1ull << bz) - 1ull));
            out[(size_t)b * TOPN + pos] = topBoxes[(size_t)b * NPAD + i];
        }
    }
}

// ---------------------------------------------------------------------------
// Workspace layout (bytes):
//   sup      : 0           size 8*2048*32*8 = 4,194,304
//   keys     : 4,194,304   size 8*36864*4   = 1,179,648
//   topBoxes : 5,373,952   size 8*2048*16   =   262,144
//   --- zero region start ---
//   hist1    : 5,636,096   size 8*65536*4   = 2,097,152
//   hist2    : 7,733,248   size 8*65536*4   = 2,097,152
//   selKeys  : 9,830,400   size 8*2048*8    =   131,072
//   params   : 9,961,472   size 512   (P[16] @0, R[16] @64, slotCtr[8] @128)
//   total    : 9,961,984 (~9.5 MB); zero region = 4,325,888 B
// ---------------------------------------------------------------------------
extern "C" void kernel_launch(void* const* d_in, const int* in_sizes, int n_in,
                              void* d_out, int out_size, void* d_ws, size_t ws_size,
                              hipStream_t stream)
{
    const float*  scores  = (const float*)d_in[0];
    const float4* offsets = (const float4*)d_in[1];
    const float*  anchors = (const float*)d_in[2];
    float4* out = (float4*)d_out;

    char* ws = (char*)d_ws;
    u64*    sup      = (u64*)(ws);
    u32*    keys     = (u32*)(ws + 4194304);
    float4* topBoxes = (float4*)(ws + 5373952);
    u32*    hist1    = (u32*)(ws + 5636096);
    u32*    hist2    = (u32*)(ws + 7733248);
    u64*    selKeys  = (u64*)(ws + 9830400);
    u32*    P        = (u32*)(ws + 9961472);
    int*    R        = (int*)(ws + 9961472 + 64);
    int*    slotCtr  = (int*)(ws + 9961472 + 128);

    const int ZERO_N = 4325888 / 16;   // hist1..params as uint4
    zero_kernel<<<(ZERO_N + 255) / 256, 256, 0, stream>>>((uint4*)(ws + 5636096), ZERO_N);
    decode_kernel<<<(BATCH * NBOX) / 256, 256, 0, stream>>>(scores, offsets, anchors, keys, hist1);
    scan_kernel<<<BATCH, 256, 0, stream>>>(hist1, nullptr, P + 0, R + 0);
    hist2_kernel<<<(BATCH * NBOX) / 256, 256, 0, stream>>>(keys, P, hist2);
    scan_kernel<<<BATCH, 256, 0, stream>>>(hist2, R + 0, P + 8, R + 8);
    compact_kernel<<<(BATCH * NBOX) / 256, 256, 0, stream>>>(keys, P, slotCtr, selKeys);
    sort_kernel<<<BATCH, 1024, 0, stream>>>(selKeys, scores, offsets, anchors, topBoxes);
    iou_kernel<<<(BATCH * TOPN * 64) / 256, 256, 0, stream>>>(topBoxes, sup);
    resolve_kernel<<<BATCH, 256, 0, stream>>>(sup, topBoxes, out);
}

// Round 5
// 170.452 us; speedup vs baseline: 3.1104x; 1.1619x over previous
//
#include <hip/hip_runtime.h>
#include <stdint.h>

// Match numpy op-for-op rounding: no FMA contraction anywhere.
#pragma clang fp contract(off)

#define BATCH 8
#define HH 64
#define WW 64
#define KA 9
#define NBOX (HH * WW * KA)   // 36864 per batch
#define TOPN 2000
#define NPAD 2048
#define NW 32                 // 64-bit words covering 2048 bits
#define IOU_T 0.7f
#define MINSZ 0.01f
#define EPSF 1e-7f
#define TSTRIDE 33            // LDS tile row stride in u64 (bank-conflict-free)

typedef unsigned int u32;
typedef unsigned long long u64;

__device__ __forceinline__ float clamp01(float x) { return fminf(fmaxf(x, 0.0f), 1.0f); }

// ---------------------------------------------------------------------------
// Shared box decode (bit-exact same arithmetic everywhere; contract off).
// ---------------------------------------------------------------------------
__device__ __forceinline__ void decode_one(
    const float* __restrict__ scores, const float4* __restrict__ offsets,
    const float* __restrict__ anchors, int gid, int t,
    float4* boxOut, u32* keyOut)
{
    int k = t % KA;
    int pos = t / KA;
    int wx = pos & (WW - 1);
    int hy = pos >> 6;
    float s = scores[gid];
    float4 off = offsets[gid];
    float aw = anchors[2 * k], ah = anchors[2 * k + 1];
    float cx = ((float)wx + 0.5f) * 16.0f;
    float cy = ((float)hy + 0.5f) * 16.0f;
    float pw = (expf(off.z) * aw) / 1024.0f;   // exp(off)*anc/img_wh
    float ph = (expf(off.w) * ah) / 1024.0f;
    float xc = (aw * off.x + cx) / 1024.0f;    // (anc*off + center)/img_wh
    float yc = (ah * off.y + cy) / 1024.0f;
    float x1 = clamp01(xc - pw * 0.5f);
    float y1 = clamp01(yc - ph * 0.5f);
    float x2 = clamp01(xc + pw * 0.5f);
    float y2 = clamp01(yc + ph * 0.5f);
    float sc = clamp01(s);
    float m = ((x2 - x1) > MINSZ && (y2 - y1) > MINSZ) ? 1.0f : 0.0f;
    *boxOut = make_float4(x1 * m, y1 * m, x2 * m, y2 * m);
    *keyOut = __float_as_uint(sc * m);   // score >= 0: bit order == value order
}

// ---------------------------------------------------------------------------
// 1) Decode score keys only (boxes DCE'd; re-decoded later for top-2000).
// ---------------------------------------------------------------------------
__global__ __launch_bounds__(256) void decode_kernel(
    const float* __restrict__ scores, const float4* __restrict__ offsets,
    const float* __restrict__ anchors, u32* __restrict__ keys)
{
    int gid = blockIdx.x * 256 + threadIdx.x;   // grid exactly covers 8*NBOX
    int b = gid / NBOX;
    int t = gid - b * NBOX;
    float4 box; u32 key;
    decode_one(scores, offsets, anchors, gid, t, &box, &key);
    keys[gid] = key;
}

// ---------------------------------------------------------------------------
// 2) Fused per-batch select: 3-pass LDS radix (12+12+8 bits) -> exact 32-bit
//    score threshold Sstar; compact keys>=Sstar into LDS; bitonic-sort 2048
//    keys desc ((score<<16)|(0xFFFF-i): score desc, index asc; ties past
//    slot 2000 fall off); re-decode top-2000 boxes. One block per batch.
// ---------------------------------------------------------------------------
__global__ __launch_bounds__(1024) void select_kernel(
    const u32* __restrict__ keys, const float* __restrict__ scores,
    const float4* __restrict__ offsets, const float* __restrict__ anchors,
    float4* __restrict__ topBoxes)
{
    int b = blockIdx.x;
    int tid = threadIdx.x;
    const u32* kb = keys + (size_t)b * NBOX;

    __shared__ u32 hist[4096];
    __shared__ u32 suf[1024];
    __shared__ u64 sel[NPAD];
    __shared__ u32 Bsh;
    __shared__ int Rsh;
    __shared__ int ctr;

    if (tid == 0) ctr = 0;
    int r = TOPN;
    u32 P1 = 0, P12 = 0, Sstar = 0;

    for (int pass = 0; pass < 3; ++pass) {
        int nb = (pass < 2) ? 4096 : 256;
        for (int i = tid; i < nb; i += 1024) hist[i] = 0;
        __syncthreads();
        for (int i = tid; i < NBOX; i += 1024) {
            u32 key = kb[i];
            u32 bin; bool ok;
            if (pass == 0)      { bin = key >> 20;          ok = true; }
            else if (pass == 1) { bin = (key >> 8) & 0xFFFu; ok = ((key >> 20) == P1); }
            else                { bin = key & 0xFFu;         ok = ((key >> 8) == P12); }
            if (ok) atomicAdd(&hist[bin], 1u);
        }
        __syncthreads();
        // descending-rank find: thread t owns bins [4t, 4t+3]
        int owners = nb / 4;
        if (tid < owners) {
            u32 s = hist[4 * tid] + hist[4 * tid + 1] + hist[4 * tid + 2] + hist[4 * tid + 3];
            suf[tid] = s;
        }
        __syncthreads();
        for (int d = 1; d < owners; d <<= 1) {
            u32 v = (tid < owners && tid + d < owners) ? suf[tid + d] : 0u;
            __syncthreads();
            if (tid < owners) suf[tid] += v;
            __syncthreads();
        }
        if (tid < owners) {
            u32 mine = suf[tid];
            u32 nxt = (tid < owners - 1) ? suf[tid + 1] : 0u;
            if (mine >= (u32)r && nxt < (u32)r) {      // exactly one thread
                u32 cum = nxt;
                for (int v = 4 * tid + 3; v >= 4 * tid; --v) {
                    u32 hv = hist[v];
                    cum += hv;
                    if (cum >= (u32)r) { Bsh = (u32)v; Rsh = r - (int)(cum - hv); break; }
                }
            }
        }
        __syncthreads();
        r = Rsh;
        if (pass == 0)      P1 = Bsh;
        else if (pass == 1) P12 = (P1 << 12) | Bsh;
        else                Sstar = (P12 << 8) | Bsh;
        __syncthreads();   // hist reused next pass
    }

    // compact keys >= Sstar into LDS (slot order arbitrary; sort follows)
    for (int i = tid; i < NPAD; i += 1024) sel[i] = 0ull;
    __syncthreads();
    for (int i = tid; i < NBOX; i += 1024) {
        u32 key = kb[i];
        bool take = (key >= Sstar);
        u64 bal = __ballot(take);
        int base = 0;
        if ((tid & 63) == 0 && bal) base = atomicAdd(&ctr, (int)__popcll(bal));
        base = __shfl(base, 0);
        if (take) {
            int slot = base + (int)__popcll(bal & ((1ull << (tid & 63)) - 1ull));
            if (slot < NPAD)   // safety vs pathological tie counts
                sel[slot] = ((u64)key << 16) | (u64)(0xFFFFu - (u32)i);
        }
    }
    __syncthreads();

    // bitonic sort 2048 desc
    for (int k = 2; k <= NPAD; k <<= 1) {
        for (int j = k >> 1; j > 0; j >>= 1) {
#pragma unroll
            for (int n = 0; n < 2; ++n) {
                int i = tid + n * 1024;
                int ixj = i ^ j;
                if (ixj > i) {
                    bool desc = ((i & k) == 0);
                    u64 a = sel[i], c = sel[ixj];
                    if (desc ? (a < c) : (a > c)) { sel[i] = c; sel[ixj] = a; }
                }
            }
            __syncthreads();
        }
    }

    // re-decode top-2000 boxes; rows 2000..2047 zeroed for safe loads
    for (int i = tid; i < NPAD; i += 1024) {
        float4 v = make_float4(0, 0, 0, 0);
        if (i < TOPN) {
            u64 K = sel[i];
            int idx = 0xFFFF - (int)(K & 0xFFFFull);
            u32 kdummy;
            decode_one(scores, offsets, anchors, b * NBOX + idx, idx, &v, &kdummy);
        }
        topBoxes[b * NPAD + i] = v;
    }
}

// ---------------------------------------------------------------------------
// 3) Suppression bitmask, upper triangle only: row r writes words w >= r>>6.
// ---------------------------------------------------------------------------
__global__ __launch_bounds__(256) void iou_kernel(
    const float4* __restrict__ topBoxes, u64* __restrict__ sup)
{
    int gid = blockIdx.x * 256 + threadIdx.x;
    int wid = gid >> 6;
    int lane = gid & 63;
    int b = wid / TOPN;
    int r = wid - b * TOPN;

    float4 A = topBoxes[(size_t)b * NPAD + r];
    float areaA = (A.z - A.x) * (A.w - A.y);
    size_t supBase = ((size_t)b * NPAD + r) * NW;

    for (int w = r >> 6; w < NW; ++w) {
        int j = w * 64 + lane;
        float4 Bx = topBoxes[(size_t)b * NPAD + j];
        float ix1 = fmaxf(A.x, Bx.x);
        float iy1 = fmaxf(A.y, Bx.y);
        float ix2 = fminf(A.z, Bx.z);
        float iy2 = fminf(A.w, Bx.w);
        float iw = fmaxf(ix2 - ix1, 0.0f);
        float ih = fmaxf(iy2 - iy1, 0.0f);
        float inter = iw * ih;
        float areaB = (Bx.z - Bx.x) * (Bx.w - Bx.y);
        float iou = inter / (areaA + areaB - inter + EPSF);
        bool s = (iou > IOU_T) && (j > r) && (j < TOPN);
        u64 m = __ballot(s);
        if (lane == 0) sup[supBase + w] = m;
    }
}

// ---------------------------------------------------------------------------
// 4) Word-blocked NMS sweep, double-buffered LDS tiles + 1-ahead register
//    prefetch. Phase 1 uses an ffs skip-loop: only KEPT boxes suppress, so
//    iterations == finally-kept count in the word (exact greedy semantics:
//    a processed bit can never be cleared later since masks only have j>i).
// ---------------------------------------------------------------------------
__global__ __launch_bounds__(256) void resolve_kernel(
    const u64* __restrict__ sup, const float4* __restrict__ topBoxes,
    float4* __restrict__ out)
{
    int b = blockIdx.x;
    int tid = threadIdx.x;
    __shared__ u64 tile[2][64 * TSTRIDE];   // 2 x 16.9 KB
    __shared__ u64 keep[NW];
    __shared__ int wbase[NW];
    if (tid < NW) keep[tid] = (tid < 31) ? ~0ull : 0xFFFFull;  // bits >=2000 off
    const u64* supB = sup + (size_t)b * NPAD * NW;
    unsigned* keep32 = (unsigned*)keep;

    int row = tid >> 2;               // 0..63
    int wcol = (tid & 3) * 8;         // base word within row (8 consecutive)

    // prologue: load + stage tile 0 (rows 0..63, all 32 words; 16 KB)
    {
        const uint4* src = (const uint4*)(supB + tid * 8);
        uint4 p0 = src[0], p1 = src[1], p2 = src[2], p3 = src[3];
        u64* d = &tile[0][row * TSTRIDE + wcol];
        d[0] = ((u64)p0.y << 32) | p0.x;  d[1] = ((u64)p0.w << 32) | p0.z;
        d[2] = ((u64)p1.y << 32) | p1.x;  d[3] = ((u64)p1.w << 32) | p1.z;
        d[4] = ((u64)p2.y << 32) | p2.x;  d[5] = ((u64)p2.w << 32) | p2.z;
        d[6] = ((u64)p3.y << 32) | p3.x;  d[7] = ((u64)p3.w << 32) | p3.z;
    }
    __syncthreads();

    for (int w = 0; w < NW; ++w) {
        int buf = w & 1;
        // issue next tile's loads early (latency hides under this iteration)
        uint4 n0, n1, n2, n3;
        if (w + 1 < NW) {
            const uint4* src = (const uint4*)(supB + (size_t)(w + 1) * 2048 + tid * 8);
            n0 = src[0]; n1 = src[1]; n2 = src[2]; n3 = src[3];
        }

        // phase 1: wave 0, ffs skip-loop over kept bits only
        if (tid < 64) {
            u64 m = tile[buf][tid * TSTRIDE + w];
            u32 mlo = (u32)m, mhi = (u32)(m >> 32);
            u64 kw = keep[w];
            u64 rem = kw;               // kept-and-unprocessed bits
            while (rem) {
                int t2 = (int)(__ffsll((unsigned long long)rem) - 1);
                u32 alo = (u32)__builtin_amdgcn_readlane((int)mlo, t2);
                u32 ahi = (u32)__builtin_amdgcn_readlane((int)mhi, t2);
                u64 mt = ((u64)ahi << 32) | alo;   // bits strictly > t2 only
                kw &= ~mt;
                rem &= ~(mt | (1ull << t2));
            }
            if (tid == 0) keep[w] = kw;
        }
        __syncthreads();

        // phase 2: apply kept rows' suppression to later words (from LDS)
        u64 kwword = keep[w];
        int w2 = tid & 31;
        int grp = tid >> 5;              // 8 rows per thread
        if (w2 > w) {
            u64 acc = 0;
#pragma unroll
            for (int q = 0; q < 8; ++q) {
                int rl = grp * 8 + q;
                if ((kwword >> rl) & 1ull)
                    acc |= tile[buf][rl * TSTRIDE + w2];
            }
            if (acc) {
                u32 lo = (u32)acc, hi = (u32)(acc >> 32);
                if (lo) atomicAnd(&keep32[2 * w2], ~lo);
                if (hi) atomicAnd(&keep32[2 * w2 + 1], ~hi);
            }
        }

        // stage next tile into the alternate buffer (prev contents consumed)
        if (w + 1 < NW) {
            u64* d = &tile[buf ^ 1][row * TSTRIDE + wcol];
            d[0] = ((u64)n0.y << 32) | n0.x;  d[1] = ((u64)n0.w << 32) | n0.z;
            d[2] = ((u64)n1.y << 32) | n1.x;  d[3] = ((u64)n1.w << 32) | n1.z;
            d[4] = ((u64)n2.y << 32) | n2.x;  d[5] = ((u64)n2.w << 32) | n2.z;
            d[6] = ((u64)n3.y << 32) | n3.x;  d[7] = ((u64)n3.w << 32) | n3.z;
        }
        __syncthreads();
    }

    if (tid == 0) {
        int s = 0;
        for (int w2 = 0; w2 < NW; ++w2) { wbase[w2] = s; s += __popcll(keep[w2]); }
    }
    __syncthreads();
    for (int i = tid; i < TOPN; i += 256)
        out[(size_t)b * TOPN + i] = make_float4(0, 0, 0, 0);
    __syncthreads();
    for (int i = tid; i < TOPN; i += 256) {
        int wi = i >> 6, bz = i & 63;
        u64 kw = keep[wi];
        if ((kw >> bz) & 1ull) {
            int pos = wbase[wi] + __popcll(kw & ((1ull << bz) - 1ull));
            out[(size_t)b * TOPN + pos] = topBoxes[(size_t)b * NPAD + i];
        }
    }
}

// ---------------------------------------------------------------------------
// Workspace layout (bytes):
//   sup      : 0           size 8*2048*32*8 = 4,194,304
//   keys     : 4,194,304   size 8*36864*4   = 1,179,648
//   topBoxes : 5,373,952   size 8*2048*16   =   262,144
//   total    : 5,636,096 (~5.4 MB); nothing needs pre-zeroing.
// ---------------------------------------------------------------------------
extern "C" void kernel_launch(void* const* d_in, const int* in_sizes, int n_in,
                              void* d_out, int out_size, void* d_ws, size_t ws_size,
                              hipStream_t stream)
{
    const float*  scores  = (const float*)d_in[0];
    const float4* offsets = (const float4*)d_in[1];
    const float*  anchors = (const float*)d_in[2];
    float4* out = (float4*)d_out;

    char* ws = (char*)d_ws;
    u64*    sup      = (u64*)(ws);
    u32*    keys     = (u32*)(ws + 4194304);
    float4* topBoxes = (float4*)(ws + 5373952);

    decode_kernel<<<(BATCH * NBOX) / 256, 256, 0, stream>>>(scores, offsets, anchors, keys);
    select_kernel<<<BATCH, 1024, 0, stream>>>(keys, scores, offsets, anchors, topBoxes);
    iou_kernel<<<(BATCH * TOPN * 64) / 256, 256, 0, stream>>>(topBoxes, sup);
    resolve_kernel<<<BATCH, 256, 0, stream>>>(sup, topBoxes, out);
}

// Round 6
// 170.215 us; speedup vs baseline: 3.1147x; 1.0014x over previous
//
#include <hip/hip_runtime.h>
#include <stdint.h>

// Match numpy op-for-op rounding: no FMA contraction anywhere.
#pragma clang fp contract(off)

#define BATCH 8
#define HH 64
#define WW 64
#define KA 9
#define NBOX (HH * WW * KA)   // 36864 per batch
#define TOPN 2000
#define NPAD 2048
#define NW 32                 // 64-bit words covering 2048 bits
#define IOU_T 0.7f
#define MINSZ 0.01f
#define EPSF 1e-7f
#define TSTRIDE 33            // LDS tile row stride in u64 (bank-conflict-free)

typedef unsigned int u32;
typedef unsigned long long u64;

__device__ __forceinline__ float clamp01(float x) { return fminf(fmaxf(x, 0.0f), 1.0f); }

// ---------------------------------------------------------------------------
// Shared box decode (bit-exact same arithmetic everywhere; contract off).
// ---------------------------------------------------------------------------
__device__ __forceinline__ void decode_one(
    const float* __restrict__ scores, const float4* __restrict__ offsets,
    const float* __restrict__ anchors, int gid, int t,
    float4* boxOut, u32* keyOut)
{
    int k = t % KA;
    int pos = t / KA;
    int wx = pos & (WW - 1);
    int hy = pos >> 6;
    float s = scores[gid];
    float4 off = offsets[gid];
    float aw = anchors[2 * k], ah = anchors[2 * k + 1];
    float cx = ((float)wx + 0.5f) * 16.0f;
    float cy = ((float)hy + 0.5f) * 16.0f;
    float pw = (expf(off.z) * aw) / 1024.0f;   // exp(off)*anc/img_wh
    float ph = (expf(off.w) * ah) / 1024.0f;
    float xc = (aw * off.x + cx) / 1024.0f;    // (anc*off + center)/img_wh
    float yc = (ah * off.y + cy) / 1024.0f;
    float x1 = clamp01(xc - pw * 0.5f);
    float y1 = clamp01(yc - ph * 0.5f);
    float x2 = clamp01(xc + pw * 0.5f);
    float y2 = clamp01(yc + ph * 0.5f);
    float sc = clamp01(s);
    float m = ((x2 - x1) > MINSZ && (y2 - y1) > MINSZ) ? 1.0f : 0.0f;
    *boxOut = make_float4(x1 * m, y1 * m, x2 * m, y2 * m);
    *keyOut = __float_as_uint(sc * m);   // score >= 0: bit order == value order
}

// ---------------------------------------------------------------------------
// 1) Decode score keys only (boxes DCE'd; re-decoded later for top-2000).
// ---------------------------------------------------------------------------
__global__ __launch_bounds__(256) void decode_kernel(
    const float* __restrict__ scores, const float4* __restrict__ offsets,
    const float* __restrict__ anchors, u32* __restrict__ keys)
{
    int gid = blockIdx.x * 256 + threadIdx.x;   // grid exactly covers 8*NBOX
    int b = gid / NBOX;
    int t = gid - b * NBOX;
    float4 box; u32 key;
    decode_one(scores, offsets, anchors, gid, t, &box, &key);
    keys[gid] = key;
}

// ---------------------------------------------------------------------------
// 2) Fused per-batch select: 3-pass LDS radix (12+12+8 bits) -> exact 32-bit
//    score threshold Sstar; compact keys>=Sstar into LDS; bitonic-sort 2048
//    keys desc ((score<<16)|(0xFFFF-i): score desc, index asc; ties past
//    slot 2000 fall off); re-decode top-2000 boxes. One block per batch.
// ---------------------------------------------------------------------------
__global__ __launch_bounds__(1024) void select_kernel(
    const u32* __restrict__ keys, const float* __restrict__ scores,
    const float4* __restrict__ offsets, const float* __restrict__ anchors,
    float4* __restrict__ topBoxes)
{
    int b = blockIdx.x;
    int tid = threadIdx.x;
    const u32* kb = keys + (size_t)b * NBOX;

    __shared__ u32 hist[4096];
    __shared__ u32 suf[1024];
    __shared__ u64 sel[NPAD];
    __shared__ u32 Bsh;
    __shared__ int Rsh;
    __shared__ int ctr;

    if (tid == 0) ctr = 0;
    int r = TOPN;
    u32 P1 = 0, P12 = 0, Sstar = 0;

    for (int pass = 0; pass < 3; ++pass) {
        int nb = (pass < 2) ? 4096 : 256;
        for (int i = tid; i < nb; i += 1024) hist[i] = 0;
        __syncthreads();
        for (int i = tid; i < NBOX; i += 1024) {
            u32 key = kb[i];
            u32 bin; bool ok;
            if (pass == 0)      { bin = key >> 20;          ok = true; }
            else if (pass == 1) { bin = (key >> 8) & 0xFFFu; ok = ((key >> 20) == P1); }
            else                { bin = key & 0xFFu;         ok = ((key >> 8) == P12); }
            if (ok) atomicAdd(&hist[bin], 1u);
        }
        __syncthreads();
        // descending-rank find: thread t owns bins [4t, 4t+3]
        int owners = nb / 4;
        if (tid < owners) {
            u32 s = hist[4 * tid] + hist[4 * tid + 1] + hist[4 * tid + 2] + hist[4 * tid + 3];
            suf[tid] = s;
        }
        __syncthreads();
        for (int d = 1; d < owners; d <<= 1) {
            u32 v = (tid < owners && tid + d < owners) ? suf[tid + d] : 0u;
            __syncthreads();
            if (tid < owners) suf[tid] += v;
            __syncthreads();
        }
        if (tid < owners) {
            u32 mine = suf[tid];
            u32 nxt = (tid < owners - 1) ? suf[tid + 1] : 0u;
            if (mine >= (u32)r && nxt < (u32)r) {      // exactly one thread
                u32 cum = nxt;
                for (int v = 4 * tid + 3; v >= 4 * tid; --v) {
                    u32 hv = hist[v];
                    cum += hv;
                    if (cum >= (u32)r) { Bsh = (u32)v; Rsh = r - (int)(cum - hv); break; }
                }
            }
        }
        __syncthreads();
        r = Rsh;
        if (pass == 0)      P1 = Bsh;
        else if (pass == 1) P12 = (P1 << 12) | Bsh;
        else                Sstar = (P12 << 8) | Bsh;
        __syncthreads();   // hist reused next pass
    }

    // compact keys >= Sstar into LDS (slot order arbitrary; sort follows)
    for (int i = tid; i < NPAD; i += 1024) sel[i] = 0ull;
    __syncthreads();
    for (int i = tid; i < NBOX; i += 1024) {
        u32 key = kb[i];
        bool take = (key >= Sstar);
        u64 bal = __ballot(take);
        int base = 0;
        if ((tid & 63) == 0 && bal) base = atomicAdd(&ctr, (int)__popcll(bal));
        base = __shfl(base, 0);
        if (take) {
            int slot = base + (int)__popcll(bal & ((1ull << (tid & 63)) - 1ull));
            if (slot < NPAD)   // safety vs pathological tie counts
                sel[slot] = ((u64)key << 16) | (u64)(0xFFFFu - (u32)i);
        }
    }
    __syncthreads();

    // bitonic sort 2048 desc
    for (int k = 2; k <= NPAD; k <<= 1) {
        for (int j = k >> 1; j > 0; j >>= 1) {
#pragma unroll
            for (int n = 0; n < 2; ++n) {
                int i = tid + n * 1024;
                int ixj = i ^ j;
                if (ixj > i) {
                    bool desc = ((i & k) == 0);
                    u64 a = sel[i], c = sel[ixj];
                    if (desc ? (a < c) : (a > c)) { sel[i] = c; sel[ixj] = a; }
                }
            }
            __syncthreads();
        }
    }

    // re-decode top-2000 boxes; rows 2000..2047 zeroed for safe loads
    for (int i = tid; i < NPAD; i += 1024) {
        float4 v = make_float4(0, 0, 0, 0);
        if (i < TOPN) {
            u64 K = sel[i];
            int idx = 0xFFFF - (int)(K & 0xFFFFull);
            u32 kdummy;
            decode_one(scores, offsets, anchors, b * NBOX + idx, idx, &v, &kdummy);
        }
        topBoxes[b * NPAD + i] = v;
    }
}

// ---------------------------------------------------------------------------
// 3) Suppression bitmask, upper triangle only: row r writes words w >= r>>6.
// ---------------------------------------------------------------------------
__global__ __launch_bounds__(256) void iou_kernel(
    const float4* __restrict__ topBoxes, u64* __restrict__ sup)
{
    int gid = blockIdx.x * 256 + threadIdx.x;
    int wid = gid >> 6;
    int lane = gid & 63;
    int b = wid / TOPN;
    int r = wid - b * TOPN;

    float4 A = topBoxes[(size_t)b * NPAD + r];
    float areaA = (A.z - A.x) * (A.w - A.y);
    size_t supBase = ((size_t)b * NPAD + r) * NW;

    for (int w = r >> 6; w < NW; ++w) {
        int j = w * 64 + lane;
        float4 Bx = topBoxes[(size_t)b * NPAD + j];
        float ix1 = fmaxf(A.x, Bx.x);
        float iy1 = fmaxf(A.y, Bx.y);
        float ix2 = fminf(A.z, Bx.z);
        float iy2 = fminf(A.w, Bx.w);
        float iw = fmaxf(ix2 - ix1, 0.0f);
        float ih = fmaxf(iy2 - iy1, 0.0f);
        float inter = iw * ih;
        float areaB = (Bx.z - Bx.x) * (Bx.w - Bx.y);
        float iou = inter / (areaA + areaB - inter + EPSF);
        bool s = (iou > IOU_T) && (j > r) && (j < TOPN);
        u64 m = __ballot(s);
        if (lane == 0) sup[supBase + w] = m;
    }
}

// ---------------------------------------------------------------------------
// 4) Word-blocked NMS sweep, double-buffered LDS tiles + 1-ahead register
//    prefetch. Phase 1 uses an ffs skip-loop: only KEPT boxes suppress, so
//    iterations == finally-kept count in the word (exact greedy semantics:
//    a processed bit can never be cleared later since masks only have j>i).
// ---------------------------------------------------------------------------
__global__ __launch_bounds__(256) void resolve_kernel(
    const u64* __restrict__ sup, const float4* __restrict__ topBoxes,
    float4* __restrict__ out)
{
    int b = blockIdx.x;
    int tid = threadIdx.x;
    __shared__ u64 tile[2][64 * TSTRIDE];   // 2 x 16.9 KB
    __shared__ u64 keep[NW];
    __shared__ int wbase[NW];
    if (tid < NW) keep[tid] = (tid < 31) ? ~0ull : 0xFFFFull;  // bits >=2000 off
    const u64* supB = sup + (size_t)b * NPAD * NW;
    unsigned* keep32 = (unsigned*)keep;

    int row = tid >> 2;               // 0..63
    int wcol = (tid & 3) * 8;         // base word within row (8 consecutive)

    // prologue: load + stage tile 0 (rows 0..63, all 32 words; 16 KB)
    {
        const uint4* src = (const uint4*)(supB + tid * 8);
        uint4 p0 = src[0], p1 = src[1], p2 = src[2], p3 = src[3];
        u64* d = &tile[0][row * TSTRIDE + wcol];
        d[0] = ((u64)p0.y << 32) | p0.x;  d[1] = ((u64)p0.w << 32) | p0.z;
        d[2] = ((u64)p1.y << 32) | p1.x;  d[3] = ((u64)p1.w << 32) | p1.z;
        d[4] = ((u64)p2.y << 32) | p2.x;  d[5] = ((u64)p2.w << 32) | p2.z;
        d[6] = ((u64)p3.y << 32) | p3.x;  d[7] = ((u64)p3.w << 32) | p3.z;
    }
    __syncthreads();

    for (int w = 0; w < NW; ++w) {
        int buf = w & 1;
        // issue next tile's loads early (latency hides under this iteration)
        uint4 n0, n1, n2, n3;
        if (w + 1 < NW) {
            const uint4* src = (const uint4*)(supB + (size_t)(w + 1) * 2048 + tid * 8);
            n0 = src[0]; n1 = src[1]; n2 = src[2]; n3 = src[3];
        }

        // phase 1: wave 0, ffs skip-loop over kept bits only
        if (tid < 64) {
            u64 m = tile[buf][tid * TSTRIDE + w];
            u32 mlo = (u32)m, mhi = (u32)(m >> 32);
            u64 kw = keep[w];
            u64 rem = kw;               // kept-and-unprocessed bits
            while (rem) {
                int t2 = (int)(__ffsll((unsigned long long)rem) - 1);
                u32 alo = (u32)__builtin_amdgcn_readlane((int)mlo, t2);
                u32 ahi = (u32)__builtin_amdgcn_readlane((int)mhi, t2);
                u64 mt = ((u64)ahi << 32) | alo;   // bits strictly > t2 only
                kw &= ~mt;
                rem &= ~(mt | (1ull << t2));
            }
            if (tid == 0) keep[w] = kw;
        }
        __syncthreads();

        // phase 2: apply kept rows' suppression to later words (from LDS)
        u64 kwword = keep[w];
        int w2 = tid & 31;
        int grp = tid >> 5;              // 8 rows per thread
        if (w2 > w) {
            u64 acc = 0;
#pragma unroll
            for (int q = 0; q < 8; ++q) {
                int rl = grp * 8 + q;
                if ((kwword >> rl) & 1ull)
                    acc |= tile[buf][rl * TSTRIDE + w2];
            }
            if (acc) {
                u32 lo = (u32)acc, hi = (u32)(acc >> 32);
                if (lo) atomicAnd(&keep32[2 * w2], ~lo);
                if (hi) atomicAnd(&keep32[2 * w2 + 1], ~hi);
            }
        }

        // stage next tile into the alternate buffer (prev contents consumed)
        if (w + 1 < NW) {
            u64* d = &tile[buf ^ 1][row * TSTRIDE + wcol];
            d[0] = ((u64)n0.y << 32) | n0.x;  d[1] = ((u64)n0.w << 32) | n0.z;
            d[2] = ((u64)n1.y << 32) | n1.x;  d[3] = ((u64)n1.w << 32) | n1.z;
            d[4] = ((u64)n2.y << 32) | n2.x;  d[5] = ((u64)n2.w << 32) | n2.z;
            d[6] = ((u64)n3.y << 32) | n3.x;  d[7] = ((u64)n3.w << 32) | n3.z;
        }
        __syncthreads();
    }

    if (tid == 0) {
        int s = 0;
        for (int w2 = 0; w2 < NW; ++w2) { wbase[w2] = s; s += __popcll(keep[w2]); }
    }
    __syncthreads();
    for (int i = tid; i < TOPN; i += 256)
        out[(size_t)b * TOPN + i] = make_float4(0, 0, 0, 0);
    __syncthreads();
    for (int i = tid; i < TOPN; i += 256) {
        int wi = i >> 6, bz = i & 63;
        u64 kw = keep[wi];
        if ((kw >> bz) & 1ull) {
            int pos = wbase[wi] + __popcll(kw & ((1ull << bz) - 1ull));
            out[(size_t)b * TOPN + pos] = topBoxes[(size_t)b * NPAD + i];
        }
    }
}

// ---------------------------------------------------------------------------
// Workspace layout (bytes):
//   sup      : 0           size 8*2048*32*8 = 4,194,304
//   keys     : 4,194,304   size 8*36864*4   = 1,179,648
//   topBoxes : 5,373,952   size 8*2048*16   =   262,144
//   total    : 5,636,096 (~5.4 MB); nothing needs pre-zeroing.
// ---------------------------------------------------------------------------
extern "C" void kernel_launch(void* const* d_in, const int* in_sizes, int n_in,
                              void* d_out, int out_size, void* d_ws, size_t ws_size,
                              hipStream_t stream)
{
    const float*  scores  = (const float*)d_in[0];
    const float4* offsets = (const float4*)d_in[1];
    const float*  anchors = (const float*)d_in[2];
    float4* out = (float4*)d_out;

    char* ws = (char*)d_ws;
    u64*    sup      = (u64*)(ws);
    u32*    keys     = (u32*)(ws + 4194304);
    float4* topBoxes = (float4*)(ws + 5373952);

    decode_kernel<<<(BATCH * NBOX) / 256, 256, 0, stream>>>(scores, offsets, anchors, keys);
    select_kernel<<<BATCH, 1024, 0, stream>>>(keys, scores, offsets, anchors, topBoxes);
    iou_kernel<<<(BATCH * TOPN * 64) / 256, 256, 0, stream>>>(topBoxes, sup);
    resolve_kernel<<<BATCH, 256, 0, stream>>>(sup, topBoxes, out);
}